// Round 9
// baseline (3088.050 us; speedup 1.0000x reference)
//
#include <hip/hip_runtime.h>
#include <hip/hip_bf16.h>

// DA block (DANet) — Round 9: OUTPUT IS FP32 (reference output dtype; per harness
// rule "bfloat16 -> __hip_bfloat16*, else float*"). The 15.6875 plateau across
// R2/R4-R8 was bf16 halfwords written into an fp32 buffer (half-rate downsample
// + zeroed tail) — implementation-independent and input-rounding-invariant,
// which matches all nine rounds of evidence. Inputs fp32, dict order.
// out = gamma_pam*pam + gamma_cam*cam + 2*x
// Compute kernels: naive R6 anchor (optimize only after green).

#define B_ 2
#define C_ 256
#define N_ 4096
#define QK_ 32

// ---- k_proj: outT[b,n,o] = bias[o] + sum_c W[o,c] * x[b,c,n] ----
__global__ __launch_bounds__(256) void k_proj(
    const float* __restrict__ x, const float* __restrict__ W, const float* __restrict__ bias,
    float* __restrict__ outT, int O) {
  int n = blockIdx.x * 256 + threadIdx.x;
  int o = blockIdx.y;
  int b = blockIdx.z;
  float acc = bias[o];
  const float* xp = x + (size_t)b * C_ * N_ + n;
  const float* wp = W + (size_t)o * C_;
  for (int c = 0; c < C_; c++) acc += wp[c] * xp[(size_t)c * N_];
  outT[((size_t)b * N_ + n) * O + o] = acc;
}

// ---- k_pam: one block per attention row i; 3 simple passes (m, l, PV) ----
__global__ __launch_bounds__(256) void k_pam(
    const float* __restrict__ qT, const float* __restrict__ kT, const float* __restrict__ vT,
    float* __restrict__ pamT) {
  int i = blockIdx.x, b = blockIdx.y;
  int tid = threadIdx.x;
  __shared__ float qs[QK_];
  __shared__ float red[256];
  __shared__ float ps[256];
  if (tid < QK_) qs[tid] = qT[((size_t)b * N_ + i) * QK_ + tid];
  __syncthreads();
  float lm = -1e30f;
  for (int j = tid; j < N_; j += 256) {
    const float* kr = kT + ((size_t)b * N_ + j) * QK_;
    float s = 0.f;
    for (int o = 0; o < QK_; o++) s += qs[o] * kr[o];
    lm = fmaxf(lm, s);
  }
  red[tid] = lm;
  __syncthreads();
  for (int st = 128; st >= 1; st >>= 1) {
    if (tid < st) red[tid] = fmaxf(red[tid], red[tid + st]);
    __syncthreads();
  }
  float m = red[0];
  __syncthreads();
  float ls = 0.f;
  for (int j = tid; j < N_; j += 256) {
    const float* kr = kT + ((size_t)b * N_ + j) * QK_;
    float s = 0.f;
    for (int o = 0; o < QK_; o++) s += qs[o] * kr[o];
    ls += __expf(s - m);
  }
  red[tid] = ls;
  __syncthreads();
  for (int st = 128; st >= 1; st >>= 1) {
    if (tid < st) red[tid] += red[tid + st];
    __syncthreads();
  }
  float inv = 1.0f / red[0];
  float acc = 0.f;
  for (int j0 = 0; j0 < N_; j0 += 256) {
    __syncthreads();
    {
      const float* kr = kT + ((size_t)b * N_ + j0 + tid) * QK_;
      float s = 0.f;
      for (int o = 0; o < QK_; o++) s += qs[o] * kr[o];
      ps[tid] = __expf(s - m) * inv;
    }
    __syncthreads();
    for (int jj = 0; jj < 256; jj++) acc += ps[jj] * vT[((size_t)b * N_ + j0 + jj) * C_ + tid];
  }
  pamT[((size_t)b * N_ + i) * C_ + tid] = acc;
}

// ---- k_cam: one block per channel-row i; thread = j. softmax(-e). ----
__global__ __launch_bounds__(256) void k_cam(const float* __restrict__ x, float* __restrict__ attnC) {
  int i = blockIdx.x, b = blockIdx.y;
  int j = threadIdx.x;
  const float* xi = x + ((size_t)b * C_ + i) * N_;
  const float* xj = x + ((size_t)b * C_ + j) * N_;
  float e = 0.f;
  for (int n = 0; n < N_; n++) e += xi[n] * xj[n];
  float ne = -e;   // softmax(rowmax - e) == softmax(-e)
  __shared__ float red[256];
  red[j] = ne;
  __syncthreads();
  for (int st = 128; st >= 1; st >>= 1) {
    if (j < st) red[j] = fmaxf(red[j], red[j + st]);
    __syncthreads();
  }
  float m = red[0];
  __syncthreads();
  float p = __expf(ne - m);
  red[j] = p;
  __syncthreads();
  for (int st = 128; st >= 1; st >>= 1) {
    if (j < st) red[j] += red[j + st];
    __syncthreads();
  }
  attnC[((size_t)b * C_ + i) * C_ + j] = p / red[0];
}

// ---- k_out: out[b,c,n] = gp*pamT[b,n,c] + gc*sum_j attnC[c,j] x[b,j,n] + 2 x[b,c,n] ----
__global__ __launch_bounds__(256) void k_out(
    const float* __restrict__ x, const float* __restrict__ attnC, const float* __restrict__ pamT,
    const float* __restrict__ gpam, const float* __restrict__ gcam, float* __restrict__ out) {
  int n = blockIdx.x * 256 + threadIdx.x;
  int c = blockIdx.y;
  int b = blockIdx.z;
  const float* arow = attnC + ((size_t)b * C_ + c) * C_;
  float acc = 0.f;
  for (int j = 0; j < C_; j++) acc += arow[j] * x[((size_t)b * C_ + j) * N_ + n];
  float pam = pamT[((size_t)b * N_ + n) * C_ + c];
  size_t idx = ((size_t)b * C_ + c) * N_ + n;
  out[idx] = gpam[0] * pam + gcam[0] * acc + 2.0f * x[idx];
}

extern "C" void kernel_launch(void* const* d_in, const int* in_sizes, int n_in,
                              void* d_out, int out_size, void* d_ws, size_t ws_size,
                              hipStream_t stream) {
  const float* x  = (const float*)d_in[0];
  const float* wq = (const float*)d_in[1];
  const float* bq = (const float*)d_in[2];
  const float* wk = (const float*)d_in[3];
  const float* bk = (const float*)d_in[4];
  const float* wv = (const float*)d_in[5];
  const float* bv = (const float*)d_in[6];
  const float* gp = (const float*)d_in[7];
  const float* gc = (const float*)d_in[8];
  float* out = (float*)d_out;   // fp32 output — the reference's output dtype

  float* ws = (float*)d_ws;
  size_t o = 0;
  float* qT    = ws + o; o += (size_t)B_ * N_ * QK_;   // 262144   (b,n,o)
  float* kT    = ws + o; o += (size_t)B_ * N_ * QK_;   // 262144   (b,n,o)
  float* vT    = ws + o; o += (size_t)B_ * N_ * C_;    // 2097152  (b,n,c)
  float* pamT  = ws + o; o += (size_t)B_ * N_ * C_;    // 2097152  (b,n,c)
  float* attnC = ws + o; o += (size_t)B_ * C_ * C_;    // 131072   (b,i,j)
  // total 4,849,664 floats = 19.4 MB

  k_proj<<<dim3(N_ / 256, QK_, B_), dim3(256), 0, stream>>>(x, wq, bq, qT, QK_);
  k_proj<<<dim3(N_ / 256, QK_, B_), dim3(256), 0, stream>>>(x, wk, bk, kT, QK_);
  k_proj<<<dim3(N_ / 256, C_, B_), dim3(256), 0, stream>>>(x, wv, bv, vT, C_);
  k_pam<<<dim3(N_, B_), dim3(256), 0, stream>>>(qT, kT, vT, pamT);
  k_cam<<<dim3(C_, B_), dim3(256), 0, stream>>>(x, attnC);
  k_out<<<dim3(N_ / 256, C_, B_), dim3(256), 0, stream>>>(x, attnC, pamT, gp, gc, out);
}

// Round 10
// 678.311 us; speedup vs baseline: 4.5526x; 4.5526x over previous
//
#include <hip/hip_runtime.h>
#include <hip/hip_bf16.h>

// DA block (DANet) — Round 10: first optimization round from the green R9 baseline.
// k_pam (2765 us, latency-bound scalar loads, MfmaUtil=0) replaced by:
//   k_pa (online m/l, fp32, R2-validated) + k_comb + k_pbm (P·V via
//   mfma_f32_16x16x32_bf16; P fp32->bf16, V staged bf16 [b][c][j]).
// CAM: R2's tiled k_ce/k_cs/k_co (validated bit-close to naive in R6/R2 A/B).
// Inputs fp32 dict order; OUTPUT fp32.
// out = gamma_pam*pam + gamma_cam*cam + 2*x

#define B_ 2
#define C_ 256
#define N_ 4096
#define QK_ 32

typedef __hip_bfloat16 bf16;
typedef __attribute__((ext_vector_type(8))) short bf16x8f;   // MFMA A/B frag (8 bf16)
typedef __attribute__((ext_vector_type(4))) float f32x4;     // MFMA C/D frag

// ---- k_qk: qT/kT[b,n,o] = bias[o] + sum_c W[o,c] x[b,c,n]  (fp32) ----
__global__ __launch_bounds__(256) void k_qk(
    const float* __restrict__ x, const float* __restrict__ wq, const float* __restrict__ wk,
    const float* __restrict__ bq, const float* __restrict__ bk,
    float* __restrict__ qT, float* __restrict__ kT) {
  int b = blockIdx.y;
  int n = blockIdx.x * 256 + threadIdx.x;
  float qa[QK_], ka[QK_];
#pragma unroll
  for (int o = 0; o < QK_; o++) { qa[o] = bq[o]; ka[o] = bk[o]; }
  const float* xp = x + (size_t)b * C_ * N_ + n;
  for (int c = 0; c < C_; c++) {
    float xv = xp[(size_t)c * N_];
#pragma unroll
    for (int o = 0; o < QK_; o++) {
      qa[o] += wq[o * C_ + c] * xv;
      ka[o] += wk[o * C_ + c] * xv;
    }
  }
  float4* qo = (float4*)(qT + ((size_t)b * N_ + n) * QK_);
  float4* ko = (float4*)(kT + ((size_t)b * N_ + n) * QK_);
#pragma unroll
  for (int u = 0; u < 8; u++) {
    qo[u] = make_float4(qa[4 * u], qa[4 * u + 1], qa[4 * u + 2], qa[4 * u + 3]);
    ko[u] = make_float4(ka[4 * u], ka[4 * u + 1], ka[4 * u + 2], ka[4 * u + 3]);
  }
}

// ---- k_vbf: V proj -> vbf[b,c,j] in bf16 (B-operand-friendly layout) ----
__global__ __launch_bounds__(256) void k_vbf(
    const float* __restrict__ x, const float* __restrict__ wv, const float* __restrict__ bv,
    bf16* __restrict__ vbf) {
  int b = blockIdx.z;
  int co0 = blockIdx.y * 32;
  int n0 = blockIdx.x * 256;
  int tid = threadIdx.x;
  float acc[32];
#pragma unroll
  for (int o = 0; o < 32; o++) acc[o] = bv[co0 + o];
  const float* xp = x + (size_t)b * C_ * N_ + n0 + tid;
  for (int c = 0; c < C_; c++) {
    float xv = xp[(size_t)c * N_];
#pragma unroll
    for (int o = 0; o < 32; o++) acc[o] += wv[(co0 + o) * C_ + c] * xv;
  }
  __shared__ float vs[256 * 33];
#pragma unroll
  for (int o = 0; o < 32; o++) vs[tid * 33 + o] = acc[o];
  __syncthreads();
#pragma unroll
  for (int o = 0; o < 32; o++)
    vbf[((size_t)b * C_ + co0 + o) * N_ + n0 + tid] = __float2bfloat16(vs[tid * 33 + o]);
}

// ---- k_pa: PAM pass A — chunked online (m,l), fp32 (R2-validated) ----
__global__ __launch_bounds__(256) void k_pa(
    const float* __restrict__ qT, const float* __restrict__ kT,
    float* __restrict__ pm, float* __restrict__ pl) {
  int b = blockIdx.z;
  int jc = blockIdx.y;                       // 8 chunks of 512 j's
  int i = blockIdx.x * 256 + threadIdx.x;
  float q[QK_];
  const float4* qp = (const float4*)(qT + ((size_t)b * N_ + i) * QK_);
#pragma unroll
  for (int u = 0; u < 8; u++) {
    float4 t = qp[u];
    q[4 * u] = t.x; q[4 * u + 1] = t.y; q[4 * u + 2] = t.z; q[4 * u + 3] = t.w;
  }
  __shared__ float kl[64 * QK_];
  float m = -1e30f, l = 0.f;
  int j0 = jc * 512;
  for (int jt = 0; jt < 512; jt += 64) {
    __syncthreads();
    const float4* src = (const float4*)(kT + ((size_t)b * N_ + j0 + jt) * QK_);
    float4* d = (float4*)kl;
    d[threadIdx.x] = src[threadIdx.x];
    d[threadIdx.x + 256] = src[threadIdx.x + 256];
    __syncthreads();
#pragma unroll 2
    for (int j = 0; j < 64; j++) {
      const float4* kv = (const float4*)(kl + j * QK_);
      float s = 0.f;
#pragma unroll
      for (int u = 0; u < 8; u++) {
        float4 t = kv[u];
        s += q[4 * u] * t.x + q[4 * u + 1] * t.y + q[4 * u + 2] * t.z + q[4 * u + 3] * t.w;
      }
      float nm = fmaxf(m, s);
      l = l * __expf(m - nm) + __expf(s - nm);
      m = nm;
    }
  }
  pm[((size_t)b * 8 + jc) * N_ + i] = m;
  pl[((size_t)b * 8 + jc) * N_ + i] = l;
}

// ---- k_comb: merge pass-A partials -> mrow, 1/l ----
__global__ __launch_bounds__(256) void k_comb(
    const float* __restrict__ pm, const float* __restrict__ pl,
    float* __restrict__ mrow, float* __restrict__ lrowi) {
  int t = blockIdx.x * 256 + threadIdx.x;
  int b = t >> 12, i = t & (N_ - 1);
  float M = -1e30f;
  float pmv[8];
#pragma unroll
  for (int c = 0; c < 8; c++) {
    pmv[c] = pm[((size_t)b * 8 + c) * N_ + i];
    M = fmaxf(M, pmv[c]);
  }
  float L = 0.f;
#pragma unroll
  for (int c = 0; c < 8; c++) L += pl[((size_t)b * 8 + c) * N_ + i] * __expf(pmv[c] - M);
  mrow[t] = M;
  lrowi[t] = 1.0f / L;
}

// ---- k_pbm: PAM pass B via MFMA. pamT[b,i,c] = sum_j P(i,j) V[j,c] ----
// Block = 32 i-rows, 256 threads = 4 waves; wave w owns channels [w*64, w*64+64).
// Per j-tile (32): stage k (fp32), stage V^T tile (bf16 [c][j], pitch 40),
// compute P in fp32 -> bf16 LDS (A-layout rows), then 8 MFMAs/wave.
__global__ __launch_bounds__(256) void k_pbm(
    const float* __restrict__ qT, const float* __restrict__ kT, const bf16* __restrict__ vbf,
    const float* __restrict__ mrow, const float* __restrict__ lrowi,
    float* __restrict__ pamT) {
  int b = blockIdx.y;
  int i0 = blockIdx.x * 32;
  int tid = threadIdx.x;
  int lane = tid & 63, wave = tid >> 6;
  int n16 = lane & 15, quad = lane >> 4;

  __shared__ float q_s[32 * 33];
  __shared__ float k_s[32 * 33];
  __shared__ float m_s[32], li_s[32];
  __shared__ __align__(16) bf16 p_s[32 * 40];    // [i][j], pitch 40 bf16 = 80 B
  __shared__ __align__(16) bf16 v_s[256 * 40];   // [c][j], pitch 40 bf16 = 80 B

#pragma unroll
  for (int k = 0; k < 4; k++) {
    int e = k * 256 + tid;
    int r = e >> 5, c = e & 31;
    q_s[r * 33 + c] = qT[((size_t)b * N_ + i0 + r) * QK_ + c];
  }
  if (tid < 32) {
    m_s[tid] = mrow[b * N_ + i0 + tid];
    li_s[tid] = lrowi[b * N_ + i0 + tid];
  }

  f32x4 acc[2][4];
#pragma unroll
  for (int ih = 0; ih < 2; ih++)
#pragma unroll
    for (int cb = 0; cb < 4; cb++) acc[ih][cb] = (f32x4)(0.f);

  for (int j0 = 0; j0 < N_; j0 += 32) {
    __syncthreads();   // prev-iter MFMA reads done before restaging
    // stage K tile (32x32 fp32)
#pragma unroll
    for (int k = 0; k < 4; k++) {
      int e = k * 256 + tid;
      int r = e >> 5, c = e & 31;
      k_s[r * 33 + c] = kT[((size_t)b * N_ + j0 + r) * QK_ + c];
    }
    // stage V^T tile: thread t -> channel c=t, 32 bf16 (64 B contiguous)
    {
      const int4* s4 = (const int4*)(vbf + ((size_t)b * C_ + tid) * N_ + j0);
      int4 a0 = s4[0], a1 = s4[1], a2 = s4[2], a3 = s4[3];
      int4* d4 = (int4*)(v_s + tid * 40);
      d4[0] = a0; d4[1] = a1; d4[2] = a2; d4[3] = a3;
    }
    __syncthreads();
    // P tile: thread (pi=tid&31, jg=tid>>5) computes 4 j's
    {
      int pi = tid & 31, jg = tid >> 5;
      float mi = m_s[pi], li = li_s[pi];
#pragma unroll
      for (int u = 0; u < 4; u++) {
        int j = jg * 4 + u;
        float s = 0.f;
#pragma unroll
        for (int c = 0; c < 32; c++) s += q_s[pi * 33 + c] * k_s[j * 33 + c];
        p_s[pi * 40 + j] = __float2bfloat16(__expf(s - mi) * li);
      }
    }
    __syncthreads();
    // MFMA: A[m=lane&15][k=quad*8+j] from p_s; B[n=lane&15][k=quad*8+j] from v_s
    bf16x8f afrag[2], bfrag[4];
#pragma unroll
    for (int ih = 0; ih < 2; ih++)
      afrag[ih] = *(const bf16x8f*)(const void*)(p_s + (ih * 16 + n16) * 40 + quad * 8);
#pragma unroll
    for (int cb = 0; cb < 4; cb++)
      bfrag[cb] = *(const bf16x8f*)(const void*)(v_s + (wave * 64 + cb * 16 + n16) * 40 + quad * 8);
#pragma unroll
    for (int ih = 0; ih < 2; ih++)
#pragma unroll
      for (int cb = 0; cb < 4; cb++)
        acc[ih][cb] = __builtin_amdgcn_mfma_f32_16x16x32_bf16(afrag[ih], bfrag[cb], acc[ih][cb], 0, 0, 0);
  }
  // write back: C/D layout col = lane&15, row = quad*4 + reg
#pragma unroll
  for (int ih = 0; ih < 2; ih++)
#pragma unroll
    for (int cb = 0; cb < 4; cb++) {
      int c = wave * 64 + cb * 16 + n16;
#pragma unroll
      for (int r = 0; r < 4; r++) {
        int i = ih * 16 + quad * 4 + r;
        pamT[((size_t)b * N_ + i0 + i) * C_ + c] = acc[ih][cb][r];
      }
    }
}

// ---- k_ce: CAM energy partials over K-chunks (R2-validated) ----
__global__ __launch_bounds__(256) void k_ce(const float* __restrict__ x, float* __restrict__ eCp) {
  int b = blockIdx.z;
  int kc = blockIdx.y;
  int it = blockIdx.x & 7, jt = blockIdx.x >> 3;
  int i0 = it * 32, j0 = jt * 32;
  __shared__ float xi[32 * 65], xj[32 * 65];
  int tid = threadIdx.x;
  int ti2 = (tid & 15) * 2, tj2 = (tid >> 4) * 2;
  float a00 = 0.f, a01 = 0.f, a10 = 0.f, a11 = 0.f;
  for (int n0 = 0; n0 < 512; n0 += 64) {
    __syncthreads();
#pragma unroll
    for (int k = 0; k < 8; k++) {
      int e = k * 256 + tid;
      int r = e >> 6, c = e & 63;
      xi[r * 65 + c] = x[((size_t)b * C_ + i0 + r) * N_ + kc * 512 + n0 + c];
      xj[r * 65 + c] = x[((size_t)b * C_ + j0 + r) * N_ + kc * 512 + n0 + c];
    }
    __syncthreads();
#pragma unroll 4
    for (int n = 0; n < 64; n++) {
      float u0 = xi[ti2 * 65 + n], u1 = xi[(ti2 + 1) * 65 + n];
      float w0 = xj[tj2 * 65 + n], w1 = xj[(tj2 + 1) * 65 + n];
      a00 += u0 * w0; a01 += u0 * w1; a10 += u1 * w0; a11 += u1 * w1;
    }
  }
  float* dst = eCp + (((size_t)kc * B_ + b) * C_ + i0) * C_ + j0;
  dst[(ti2 + 0) * C_ + tj2 + 0] = a00;
  dst[(ti2 + 0) * C_ + tj2 + 1] = a01;
  dst[(ti2 + 1) * C_ + tj2 + 0] = a10;
  dst[(ti2 + 1) * C_ + tj2 + 1] = a11;
}

// ---- k_cs: CAM softmax over -e (LDS tree) ----
__global__ __launch_bounds__(256) void k_cs(const float* __restrict__ eCp, float* __restrict__ attnC) {
  int row = blockIdx.x;
  int b = row >> 8, i = row & 255;
  int j = threadIdx.x;
  float e = 0.f;
#pragma unroll
  for (int kc = 0; kc < 8; kc++) e += eCp[(((size_t)kc * B_ + b) * C_ + i) * C_ + j];
  float ne = -e;
  __shared__ float buf[256];
  buf[j] = ne;
  __syncthreads();
  for (int st = 128; st >= 1; st >>= 1) {
    if (j < st) buf[j] = fmaxf(buf[j], buf[j + st]);
    __syncthreads();
  }
  float m = buf[0];
  __syncthreads();
  float p = __expf(ne - m);
  buf[j] = p;
  __syncthreads();
  for (int st = 128; st >= 1; st >>= 1) {
    if (j < st) buf[j] += buf[j + st];
    __syncthreads();
  }
  attnC[(size_t)row * C_ + j] = p / buf[0];
}

// ---- k_co: CAM out + combine -> fp32 out ----
__global__ __launch_bounds__(256) void k_co(
    const float* __restrict__ x, const float* __restrict__ attnC, const float* __restrict__ pamT,
    const float* __restrict__ gpam, const float* __restrict__ gcam, float* __restrict__ out) {
  int b = blockIdx.z, c0 = blockIdx.y * 32, n0 = blockIdx.x * 256;
  int tid = threadIdx.x;
  __shared__ float pam_s[256 * 33];
#pragma unroll
  for (int k = 0; k < 32; k++) {
    int e = k * 256 + tid;
    int r = e >> 5, cc = e & 31;
    pam_s[r * 33 + cc] = pamT[((size_t)b * N_ + n0 + r) * C_ + c0 + cc];
  }
  __syncthreads();
  float acc[32];
#pragma unroll
  for (int i = 0; i < 32; i++) acc[i] = 0.f;
  const float* arow = attnC + ((size_t)b * C_ + c0) * C_;
  for (int j = 0; j < C_; j++) {
    float xv = x[((size_t)b * C_ + j) * N_ + n0 + tid];
#pragma unroll
    for (int i = 0; i < 32; i++) acc[i] += arow[i * C_ + j] * xv;
  }
  float gp = gpam[0], gc = gcam[0];
#pragma unroll
  for (int i = 0; i < 32; i++) {
    size_t idx = ((size_t)b * C_ + c0 + i) * N_ + n0 + tid;
    out[idx] = gp * pam_s[tid * 33 + i] + gc * acc[i] + 2.0f * x[idx];
  }
}

extern "C" void kernel_launch(void* const* d_in, const int* in_sizes, int n_in,
                              void* d_out, int out_size, void* d_ws, size_t ws_size,
                              hipStream_t stream) {
  const float* x  = (const float*)d_in[0];
  const float* wq = (const float*)d_in[1];
  const float* bq = (const float*)d_in[2];
  const float* wk = (const float*)d_in[3];
  const float* bk = (const float*)d_in[4];
  const float* wv = (const float*)d_in[5];
  const float* bv = (const float*)d_in[6];
  const float* gp = (const float*)d_in[7];
  const float* gc = (const float*)d_in[8];
  float* out = (float*)d_out;

  float* ws = (float*)d_ws;
  size_t o = 0;
  float* qT    = ws + o; o += (size_t)B_ * N_ * QK_;   // 262144
  float* kT    = ws + o; o += (size_t)B_ * N_ * QK_;   // 262144
  float* pamT  = ws + o; o += (size_t)B_ * N_ * C_;    // 2097152
  float* pm    = ws + o; o += (size_t)B_ * 8 * N_;     // 65536
  float* pl    = ws + o; o += (size_t)B_ * 8 * N_;     // 65536
  float* mrow  = ws + o; o += (size_t)B_ * N_;         // 8192
  float* lrowi = ws + o; o += (size_t)B_ * N_;         // 8192
  float* eCp   = ws + o; o += (size_t)8 * B_ * C_ * C_;// 1048576
  float* attnC = ws + o; o += (size_t)B_ * C_ * C_;    // 131072
  bf16*  vbf   = (bf16*)(ws + o); o += (size_t)B_ * N_ * C_ / 2;  // 2M bf16 = 1048576 floats
  // total ~5.0 M floats = 20 MB

  k_qk<<<dim3(16, B_), dim3(256), 0, stream>>>(x, wq, wk, bq, bk, qT, kT);
  k_vbf<<<dim3(16, 8, B_), dim3(256), 0, stream>>>(x, wv, bv, vbf);
  k_pa<<<dim3(16, 8, B_), dim3(256), 0, stream>>>(qT, kT, pm, pl);
  k_comb<<<dim3(32), dim3(256), 0, stream>>>(pm, pl, mrow, lrowi);
  k_pbm<<<dim3(N_ / 32, B_), dim3(256), 0, stream>>>(qT, kT, vbf, mrow, lrowi, pamT);
  k_ce<<<dim3(64, 8, B_), dim3(256), 0, stream>>>(x, eCp);
  k_cs<<<dim3(B_ * C_), dim3(256), 0, stream>>>(eCp, attnC);
  k_co<<<dim3(16, 8, B_), dim3(256), 0, stream>>>(x, attnC, pamT, gp, gc, out);
}

// Round 13
// 504.430 us; speedup vs baseline: 6.1219x; 1.3447x over previous
//
#include <hip/hip_runtime.h>
#include <hip/hip_bf16.h>

// DA block (DANet) — Round 13: k_pbm v3, race-free by construction.
//  R12 failed post-timing tripwire (stable-wrong 8.73 on replays; launch 1 OK)
//  => timing-dependent race in k_pbm. v3 removes the hazard class:
//   - K/V LDS staging is WAVE-LOCAL (wave w stages exactly the k-rows/v-channels
//     only it consumes) -> no cross-wave sync needed for k/v at all.
//   - p_s (the only cross-wave array) is DOUBLE-BUFFERED by jt&1; with the single
//     per-iteration barrier (after P write, before PV read), a wave at iter jt+1
//     writes buffer (jt+1)&1 while the slowest wave reads buffer jt&1 — disjoint;
//     no wave can reach iter jt+2 (same buffer as jt) before all waves passed the
//     iter-jt+1 barrier, which is after their jt reads.  => provably race-free.
//   - 1 barrier/iter (was 3), register prefetch kept, MFMA mappings unchanged
//     (validated by R12 launch-1 absmax 0.0625).
// Other kernels identical to tripwire-green R10. Inputs fp32 dict order; out fp32.

#define B_ 2
#define C_ 256
#define N_ 4096
#define QK_ 32

#define TI_ 32     // i-rows per block
#define TJ_ 64     // j per tile
#define CH_ 128    // channels per block
#define KP_ 40     // k/q LDS pitch (bf16) = 80 B (16-aligned)
#define VP_ 72     // v LDS pitch (bf16) = 144 B
#define PP_ 72     // p LDS pitch (bf16) = 144 B

typedef __hip_bfloat16 bf16;
typedef __attribute__((ext_vector_type(8))) short bf16x8f;   // MFMA A/B frag
typedef __attribute__((ext_vector_type(4))) float f32x4;     // MFMA C/D frag

union bf8pack { bf16 h[8]; int4 v; };

// ---- k_qk: qT/kT[b,n,o] = bias[o] + sum_c W[o,c] x[b,c,n]  (fp32) ----
__global__ __launch_bounds__(256) void k_qk(
    const float* __restrict__ x, const float* __restrict__ wq, const float* __restrict__ wk,
    const float* __restrict__ bq, const float* __restrict__ bk,
    float* __restrict__ qT, float* __restrict__ kT) {
  int b = blockIdx.y;
  int n = blockIdx.x * 256 + threadIdx.x;
  float qa[QK_], ka[QK_];
#pragma unroll
  for (int o = 0; o < QK_; o++) { qa[o] = bq[o]; ka[o] = bk[o]; }
  const float* xp = x + (size_t)b * C_ * N_ + n;
  for (int c = 0; c < C_; c++) {
    float xv = xp[(size_t)c * N_];
#pragma unroll
    for (int o = 0; o < QK_; o++) {
      qa[o] += wq[o * C_ + c] * xv;
      ka[o] += wk[o * C_ + c] * xv;
    }
  }
  float4* qo = (float4*)(qT + ((size_t)b * N_ + n) * QK_);
  float4* ko = (float4*)(kT + ((size_t)b * N_ + n) * QK_);
#pragma unroll
  for (int u = 0; u < 8; u++) {
    qo[u] = make_float4(qa[4 * u], qa[4 * u + 1], qa[4 * u + 2], qa[4 * u + 3]);
    ko[u] = make_float4(ka[4 * u], ka[4 * u + 1], ka[4 * u + 2], ka[4 * u + 3]);
  }
}

// ---- k_vbf: V proj -> vbf[b,c,j] in bf16 ----
__global__ __launch_bounds__(256) void k_vbf(
    const float* __restrict__ x, const float* __restrict__ wv, const float* __restrict__ bv,
    bf16* __restrict__ vbf) {
  int b = blockIdx.z;
  int co0 = blockIdx.y * 32;
  int n0 = blockIdx.x * 256;
  int tid = threadIdx.x;
  float acc[32];
#pragma unroll
  for (int o = 0; o < 32; o++) acc[o] = bv[co0 + o];
  const float* xp = x + (size_t)b * C_ * N_ + n0 + tid;
  for (int c = 0; c < C_; c++) {
    float xv = xp[(size_t)c * N_];
#pragma unroll
    for (int o = 0; o < 32; o++) acc[o] += wv[(co0 + o) * C_ + c] * xv;
  }
  __shared__ float vs[256 * 33];
#pragma unroll
  for (int o = 0; o < 32; o++) vs[tid * 33 + o] = acc[o];
  __syncthreads();
#pragma unroll
  for (int o = 0; o < 32; o++)
    vbf[((size_t)b * C_ + co0 + o) * N_ + n0 + tid] = __float2bfloat16(vs[tid * 33 + o]);
}

// ---- k_pa: PAM pass A — chunked online (m,l), fp32 ----
__global__ __launch_bounds__(256) void k_pa(
    const float* __restrict__ qT, const float* __restrict__ kT,
    float* __restrict__ pm, float* __restrict__ pl) {
  int b = blockIdx.z;
  int jc = blockIdx.y;
  int i = blockIdx.x * 256 + threadIdx.x;
  float q[QK_];
  const float4* qp = (const float4*)(qT + ((size_t)b * N_ + i) * QK_);
#pragma unroll
  for (int u = 0; u < 8; u++) {
    float4 t = qp[u];
    q[4 * u] = t.x; q[4 * u + 1] = t.y; q[4 * u + 2] = t.z; q[4 * u + 3] = t.w;
  }
  __shared__ float kl[64 * QK_];
  float m = -1e30f, l = 0.f;
  int j0 = jc * 512;
  for (int jt = 0; jt < 512; jt += 64) {
    __syncthreads();
    const float4* src = (const float4*)(kT + ((size_t)b * N_ + j0 + jt) * QK_);
    float4* d = (float4*)kl;
    d[threadIdx.x] = src[threadIdx.x];
    d[threadIdx.x + 256] = src[threadIdx.x + 256];
    __syncthreads();
#pragma unroll 2
    for (int j = 0; j < 64; j++) {
      const float4* kv = (const float4*)(kl + j * QK_);
      float s = 0.f;
#pragma unroll
      for (int u = 0; u < 8; u++) {
        float4 t = kv[u];
        s += q[4 * u] * t.x + q[4 * u + 1] * t.y + q[4 * u + 2] * t.z + q[4 * u + 3] * t.w;
      }
      float nm = fmaxf(m, s);
      l = l * __expf(m - nm) + __expf(s - nm);
      m = nm;
    }
  }
  pm[((size_t)b * 8 + jc) * N_ + i] = m;
  pl[((size_t)b * 8 + jc) * N_ + i] = l;
}

// ---- k_comb: merge pass-A partials -> mrow, 1/l ----
__global__ __launch_bounds__(256) void k_comb(
    const float* __restrict__ pm, const float* __restrict__ pl,
    float* __restrict__ mrow, float* __restrict__ lrowi) {
  int t = blockIdx.x * 256 + threadIdx.x;
  int b = t >> 12, i = t & (N_ - 1);
  float M = -1e30f;
  float pmv[8];
#pragma unroll
  for (int c = 0; c < 8; c++) {
    pmv[c] = pm[((size_t)b * 8 + c) * N_ + i];
    M = fmaxf(M, pmv[c]);
  }
  float L = 0.f;
#pragma unroll
  for (int c = 0; c < 8; c++) L += pl[((size_t)b * 8 + c) * N_ + i] * __expf(pmv[c] - M);
  mrow[t] = M;
  lrowi[t] = 1.0f / L;
}

// ---- k_pbm v3: pamT[b,i,c] = sum_j P(i,j) V[j,c], all-MFMA, 1 barrier/iter ----
__global__ __launch_bounds__(256) void k_pbm(
    const float* __restrict__ qT, const float* __restrict__ kT, const bf16* __restrict__ vbf,
    const float* __restrict__ mrow, const float* __restrict__ lrowi,
    float* __restrict__ pamT) {
  int b = blockIdx.z;
  int cb0 = blockIdx.y * CH_;
  int i0 = blockIdx.x * TI_;
  int tid = threadIdx.x;
  int lane = tid & 63, wave = tid >> 6;
  int n16 = lane & 15, quad = lane >> 4;

  __shared__ __align__(16) bf16 q_hi[32 * KP_], q_lo[32 * KP_];
  __shared__ __align__(16) bf16 k_hi[64 * KP_], k_lo[64 * KP_];
  __shared__ __align__(16) bf16 v_s[128 * VP_];
  __shared__ __align__(16) bf16 p_s[2][32 * PP_];   // double-buffered (cross-wave)

  // per-lane softmax row constants (rows depend only on quad)
  float mreg[8], lireg[8];
#pragma unroll
  for (int ih = 0; ih < 2; ih++)
#pragma unroll
    for (int r = 0; r < 4; r++) {
      int i = ih * 16 + quad * 4 + r;
      mreg[ih * 4 + r] = mrow[b * N_ + i0 + i];
      lireg[ih * 4 + r] = lrowi[b * N_ + i0 + i];
    }

  // stage Q once (32x32 fp32 -> hi/lo bf16); consumed cross-wave -> barrier below
  if (tid < 128) {
    int ir = tid >> 2, kq = (tid & 3) * 8;
    const float4* qs4 = (const float4*)(qT + ((size_t)b * N_ + i0 + ir) * QK_ + kq);
    float4 f0 = qs4[0], f1 = qs4[1];
    float f[8] = {f0.x, f0.y, f0.z, f0.w, f1.x, f1.y, f1.z, f1.w};
    bf8pack uh, ul;
#pragma unroll
    for (int u = 0; u < 8; u++) {
      bf16 h = __float2bfloat16(f[u]);
      uh.h[u] = h;
      ul.h[u] = __float2bfloat16(f[u] - __bfloat162float(h));
    }
    *(int4*)(q_hi + ir * KP_ + kq) = uh.v;
    *(int4*)(q_lo + ir * KP_ + kq) = ul.v;
  }

  f32x4 acc[2][2];
#pragma unroll
  for (int ih = 0; ih < 2; ih++)
#pragma unroll
    for (int cb = 0; cb < 2; cb++) acc[ih][cb] = (f32x4)(0.f);

  // staging responsibilities — WAVE-LOCAL:
  //  K: thread tid stages row jr = tid>>2 in [16*wave, 16*wave+16) = exactly the
  //     k-rows its own wave's s-MFMA reads (j = wave*16 + n16).
  //  V: thread tid stages channel vc = tid>>1 in [32*wave, 32*wave+32) = exactly
  //     the v-rows its own wave's PV MFMA reads (c = wave*32 + cb*16 + n16).
  int jr = tid >> 2, kq = (tid & 3) * 8;
  int vc = tid >> 1, vjh = (tid & 1) * 32;

  // prefetch tile 0
  float4 kf0, kf1;
  int4 vf0, vf1, vf2, vf3;
  {
    const float4* ks4 = (const float4*)(kT + ((size_t)b * N_ + jr) * QK_ + kq);
    kf0 = ks4[0]; kf1 = ks4[1];
    const int4* vs4 = (const int4*)(vbf + ((size_t)b * C_ + cb0 + vc) * N_ + vjh);
    vf0 = vs4[0]; vf1 = vs4[1]; vf2 = vs4[2]; vf3 = vs4[3];
  }

  __syncthreads();   // Q visible to all waves (q is never rewritten)

  for (int jt = 0; jt < N_ / TJ_; jt++) {
    // store prefetched K (hi/lo) and V to LDS — wave-local regions, no barrier
    {
      float f[8] = {kf0.x, kf0.y, kf0.z, kf0.w, kf1.x, kf1.y, kf1.z, kf1.w};
      bf8pack uh, ul;
#pragma unroll
      for (int u = 0; u < 8; u++) {
        bf16 h = __float2bfloat16(f[u]);
        uh.h[u] = h;
        ul.h[u] = __float2bfloat16(f[u] - __bfloat162float(h));
      }
      *(int4*)(k_hi + jr * KP_ + kq) = uh.v;
      *(int4*)(k_lo + jr * KP_ + kq) = ul.v;
      int4* vd = (int4*)(v_s + vc * VP_ + vjh);
      vd[0] = vf0; vd[1] = vf1; vd[2] = vf2; vd[3] = vf3;
    }
    // prefetch next tile into regs (latency hidden by MFMA below)
    if (jt + 1 < N_ / TJ_) {
      int j0n = (jt + 1) * TJ_;
      const float4* ks4 = (const float4*)(kT + ((size_t)b * N_ + j0n + jr) * QK_ + kq);
      kf0 = ks4[0]; kf1 = ks4[1];
      const int4* vs4 = (const int4*)(vbf + ((size_t)b * C_ + cb0 + vc) * N_ + j0n + vjh);
      vf0 = vs4[0]; vf1 = vs4[1]; vf2 = vs4[2]; vf3 = vs4[3];
    }
    // s-tile: wave reads ONLY its own k rows (same-wave RAW via lgkmcnt)
    f32x4 s[2];
    {
      bf16x8f bh = *(const bf16x8f*)(const void*)(k_hi + (wave * 16 + n16) * KP_ + quad * 8);
      bf16x8f bl = *(const bf16x8f*)(const void*)(k_lo + (wave * 16 + n16) * KP_ + quad * 8);
#pragma unroll
      for (int ih = 0; ih < 2; ih++) {
        bf16x8f ah = *(const bf16x8f*)(const void*)(q_hi + (ih * 16 + n16) * KP_ + quad * 8);
        bf16x8f al = *(const bf16x8f*)(const void*)(q_lo + (ih * 16 + n16) * KP_ + quad * 8);
        f32x4 z = (f32x4)(0.f);
        z = __builtin_amdgcn_mfma_f32_16x16x32_bf16(ah, bh, z, 0, 0, 0);
        z = __builtin_amdgcn_mfma_f32_16x16x32_bf16(al, bh, z, 0, 0, 0);
        z = __builtin_amdgcn_mfma_f32_16x16x32_bf16(ah, bl, z, 0, 0, 0);
        s[ih] = z;
      }
    }
    // P = exp(s - m) / l -> p_s[jt&1] (C-layout: col j = wave*16+n16, row quad*4+r)
    bf16* pbuf = p_s[jt & 1];
#pragma unroll
    for (int ih = 0; ih < 2; ih++)
#pragma unroll
      for (int r = 0; r < 4; r++) {
        int i = ih * 16 + quad * 4 + r;
        float p = __expf(s[ih][r] - mreg[ih * 4 + r]) * lireg[ih * 4 + r];
        pbuf[i * PP_ + wave * 16 + n16] = __float2bfloat16(p);
      }
    __syncthreads();   // the ONE barrier: P(jt) visible; bounds wave skew so the
                       // other p-buffer (jt+1) can be written while jt is read.
    // PV: A = P rows (cross-wave, this buffer), B = own-wave V rows
    bf16x8f pa0[2], pa1[2], vb0[2], vb1[2];
#pragma unroll
    for (int ih = 0; ih < 2; ih++) {
      pa0[ih] = *(const bf16x8f*)(const void*)(pbuf + (ih * 16 + n16) * PP_ + quad * 8);
      pa1[ih] = *(const bf16x8f*)(const void*)(pbuf + (ih * 16 + n16) * PP_ + 32 + quad * 8);
    }
#pragma unroll
    for (int cb = 0; cb < 2; cb++) {
      vb0[cb] = *(const bf16x8f*)(const void*)(v_s + (wave * 32 + cb * 16 + n16) * VP_ + quad * 8);
      vb1[cb] = *(const bf16x8f*)(const void*)(v_s + (wave * 32 + cb * 16 + n16) * VP_ + 32 + quad * 8);
    }
#pragma unroll
    for (int ih = 0; ih < 2; ih++)
#pragma unroll
      for (int cb = 0; cb < 2; cb++) {
        acc[ih][cb] = __builtin_amdgcn_mfma_f32_16x16x32_bf16(pa0[ih], vb0[cb], acc[ih][cb], 0, 0, 0);
        acc[ih][cb] = __builtin_amdgcn_mfma_f32_16x16x32_bf16(pa1[ih], vb1[cb], acc[ih][cb], 0, 0, 0);
      }
  }
  // epilogue: C/D layout col=lane&15 (channel), row=quad*4+r (i)
#pragma unroll
  for (int ih = 0; ih < 2; ih++)
#pragma unroll
    for (int cb = 0; cb < 2; cb++) {
      int c = cb0 + wave * 32 + cb * 16 + n16;
#pragma unroll
      for (int r = 0; r < 4; r++) {
        int i = ih * 16 + quad * 4 + r;
        pamT[((size_t)b * N_ + i0 + i) * C_ + c] = acc[ih][cb][r];
      }
    }
}

// ---- k_ce: CAM energy partials over K-chunks ----
__global__ __launch_bounds__(256) void k_ce(const float* __restrict__ x, float* __restrict__ eCp) {
  int b = blockIdx.z;
  int kc = blockIdx.y;
  int it = blockIdx.x & 7, jt = blockIdx.x >> 3;
  int i0 = it * 32, j0 = jt * 32;
  __shared__ float xi[32 * 65], xj[32 * 65];
  int tid = threadIdx.x;
  int ti2 = (tid & 15) * 2, tj2 = (tid >> 4) * 2;
  float a00 = 0.f, a01 = 0.f, a10 = 0.f, a11 = 0.f;
  for (int n0 = 0; n0 < 512; n0 += 64) {
    __syncthreads();
#pragma unroll
    for (int k = 0; k < 8; k++) {
      int e = k * 256 + tid;
      int r = e >> 6, c = e & 63;
      xi[r * 65 + c] = x[((size_t)b * C_ + i0 + r) * N_ + kc * 512 + n0 + c];
      xj[r * 65 + c] = x[((size_t)b * C_ + j0 + r) * N_ + kc * 512 + n0 + c];
    }
    __syncthreads();
#pragma unroll 4
    for (int n = 0; n < 64; n++) {
      float u0 = xi[ti2 * 65 + n], u1 = xi[(ti2 + 1) * 65 + n];
      float w0 = xj[tj2 * 65 + n], w1 = xj[(tj2 + 1) * 65 + n];
      a00 += u0 * w0; a01 += u0 * w1; a10 += u1 * w0; a11 += u1 * w1;
    }
  }
  float* dst = eCp + (((size_t)kc * B_ + b) * C_ + i0) * C_ + j0;
  dst[(ti2 + 0) * C_ + tj2 + 0] = a00;
  dst[(ti2 + 0) * C_ + tj2 + 1] = a01;
  dst[(ti2 + 1) * C_ + tj2 + 0] = a10;
  dst[(ti2 + 1) * C_ + tj2 + 1] = a11;
}

// ---- k_cs: CAM softmax over -e ----
__global__ __launch_bounds__(256) void k_cs(const float* __restrict__ eCp, float* __restrict__ attnC) {
  int row = blockIdx.x;
  int b = row >> 8, i = row & 255;
  int j = threadIdx.x;
  float e = 0.f;
#pragma unroll
  for (int kc = 0; kc < 8; kc++) e += eCp[(((size_t)kc * B_ + b) * C_ + i) * C_ + j];
  float ne = -e;
  __shared__ float buf[256];
  buf[j] = ne;
  __syncthreads();
  for (int st = 128; st >= 1; st >>= 1) {
    if (j < st) buf[j] = fmaxf(buf[j], buf[j + st]);
    __syncthreads();
  }
  float m = buf[0];
  __syncthreads();
  float p = __expf(ne - m);
  buf[j] = p;
  __syncthreads();
  for (int st = 128; st >= 1; st >>= 1) {
    if (j < st) buf[j] += buf[j + st];
    __syncthreads();
  }
  attnC[(size_t)row * C_ + j] = p / buf[0];
}

// ---- k_co: CAM out + combine -> fp32 out ----
__global__ __launch_bounds__(256) void k_co(
    const float* __restrict__ x, const float* __restrict__ attnC, const float* __restrict__ pamT,
    const float* __restrict__ gpam, const float* __restrict__ gcam, float* __restrict__ out) {
  int b = blockIdx.z, c0 = blockIdx.y * 32, n0 = blockIdx.x * 256;
  int tid = threadIdx.x;
  __shared__ float pam_s[256 * 33];
#pragma unroll
  for (int k = 0; k < 32; k++) {
    int e = k * 256 + tid;
    int r = e >> 5, cc = e & 31;
    pam_s[r * 33 + cc] = pamT[((size_t)b * N_ + n0 + r) * C_ + c0 + cc];
  }
  __syncthreads();
  float acc[32];
#pragma unroll
  for (int i = 0; i < 32; i++) acc[i] = 0.f;
  const float* arow = attnC + ((size_t)b * C_ + c0) * C_;
  for (int j = 0; j < C_; j++) {
    float xv = x[((size_t)b * C_ + j) * N_ + n0 + tid];
#pragma unroll
    for (int i = 0; i < 32; i++) acc[i] += arow[i * C_ + j] * xv;
  }
  float gp = gpam[0], gc = gcam[0];
#pragma unroll
  for (int i = 0; i < 32; i++) {
    size_t idx = ((size_t)b * C_ + c0 + i) * N_ + n0 + tid;
    out[idx] = gp * pam_s[tid * 33 + i] + gc * acc[i] + 2.0f * x[idx];
  }
}

extern "C" void kernel_launch(void* const* d_in, const int* in_sizes, int n_in,
                              void* d_out, int out_size, void* d_ws, size_t ws_size,
                              hipStream_t stream) {
  const float* x  = (const float*)d_in[0];
  const float* wq = (const float*)d_in[1];
  const float* bq = (const float*)d_in[2];
  const float* wk = (const float*)d_in[3];
  const float* bk = (const float*)d_in[4];
  const float* wv = (const float*)d_in[5];
  const float* bv = (const float*)d_in[6];
  const float* gp = (const float*)d_in[7];
  const float* gc = (const float*)d_in[8];
  float* out = (float*)d_out;

  float* ws = (float*)d_ws;
  size_t o = 0;
  float* qT    = ws + o; o += (size_t)B_ * N_ * QK_;   // 262144
  float* kT    = ws + o; o += (size_t)B_ * N_ * QK_;   // 262144
  float* pamT  = ws + o; o += (size_t)B_ * N_ * C_;    // 2097152
  float* pm    = ws + o; o += (size_t)B_ * 8 * N_;     // 65536
  float* pl    = ws + o; o += (size_t)B_ * 8 * N_;     // 65536
  float* mrow  = ws + o; o += (size_t)B_ * N_;         // 8192
  float* lrowi = ws + o; o += (size_t)B_ * N_;         // 8192
  float* eCp   = ws + o; o += (size_t)8 * B_ * C_ * C_;// 1048576
  float* attnC = ws + o; o += (size_t)B_ * C_ * C_;    // 131072
  bf16*  vbf   = (bf16*)(ws + o); o += (size_t)B_ * N_ * C_ / 2;
  // total ~5.0 M floats = 20 MB

  k_qk<<<dim3(16, B_), dim3(256), 0, stream>>>(x, wq, wk, bq, bk, qT, kT);
  k_vbf<<<dim3(16, 8, B_), dim3(256), 0, stream>>>(x, wv, bv, vbf);
  k_pa<<<dim3(16, 8, B_), dim3(256), 0, stream>>>(qT, kT, pm, pl);
  k_comb<<<dim3(32), dim3(256), 0, stream>>>(pm, pl, mrow, lrowi);
  k_pbm<<<dim3(N_ / TI_, C_ / CH_, B_), dim3(256), 0, stream>>>(qT, kT, vbf, mrow, lrowi, pamT);
  k_ce<<<dim3(64, 8, B_), dim3(256), 0, stream>>>(x, eCp);
  k_cs<<<dim3(B_ * C_), dim3(256), 0, stream>>>(eCp, attnC);
  k_co<<<dim3(16, 8, B_), dim3(256), 0, stream>>>(x, attnC, pamT, gp, gc, out);
}

// Round 14
// 432.123 us; speedup vs baseline: 7.1462x; 1.1673x over previous
//
#include <hip/hip_runtime.h>
#include <hip/hip_bf16.h>

// DA block (DANet) — Round 14: occupancy fixes on the R13-green pipeline.
//  - k_qk (measured ~115 us, VALUBusy 1.4%, 32 blocks) -> two-stage c-split:
//    k_qk1 (16x4xB=128 blocks, 64-c chunks, fp32 partials) + k_qk2 (combine+bias).
//  - k_pa: 8 -> 16 j-chunks (512 blocks = 2 blocks/CU); k_comb merges 16.
//  - k_pbm v3 (race-free, tripwire-clean) and all other kernels UNCHANGED.
// Inputs fp32 dict order; output fp32.

#define B_ 2
#define C_ 256
#define N_ 4096
#define QK_ 32
#define JC_ 16     // k_pa j-chunks

#define TI_ 32     // k_pbm i-rows per block
#define TJ_ 64     // k_pbm j per tile
#define CH_ 128    // k_pbm channels per block
#define KP_ 40     // k/q LDS pitch (bf16) = 80 B (16-aligned)
#define VP_ 72     // v LDS pitch (bf16) = 144 B
#define PP_ 72     // p LDS pitch (bf16) = 144 B

typedef __hip_bfloat16 bf16;
typedef __attribute__((ext_vector_type(8))) short bf16x8f;   // MFMA A/B frag
typedef __attribute__((ext_vector_type(4))) float f32x4;     // MFMA C/D frag

union bf8pack { bf16 h[8]; int4 v; };

// ---- k_qk1: partial Q,K projections over a 64-channel chunk ----
// qp/kp layout: [cg][b][n][32]
__global__ __launch_bounds__(256) void k_qk1(
    const float* __restrict__ x, const float* __restrict__ wq, const float* __restrict__ wk,
    float* __restrict__ qp, float* __restrict__ kp) {
  int b = blockIdx.z;
  int cg = blockIdx.y;                      // 4 chunks of 64 channels
  int n = blockIdx.x * 256 + threadIdx.x;
  float qa[QK_], ka[QK_];
#pragma unroll
  for (int o = 0; o < QK_; o++) { qa[o] = 0.f; ka[o] = 0.f; }
  const float* xp = x + ((size_t)b * C_ + cg * 64) * N_ + n;
  for (int c = 0; c < 64; c++) {
    float xv = xp[(size_t)c * N_];
    int cc = cg * 64 + c;
#pragma unroll
    for (int o = 0; o < QK_; o++) {
      qa[o] += wq[o * C_ + cc] * xv;   // uniform weight loads -> scalar path
      ka[o] += wk[o * C_ + cc] * xv;
    }
  }
  float4* qo = (float4*)(qp + (((size_t)cg * B_ + b) * N_ + n) * QK_);
  float4* ko = (float4*)(kp + (((size_t)cg * B_ + b) * N_ + n) * QK_);
#pragma unroll
  for (int u = 0; u < 8; u++) {
    qo[u] = make_float4(qa[4 * u], qa[4 * u + 1], qa[4 * u + 2], qa[4 * u + 3]);
    ko[u] = make_float4(ka[4 * u], ka[4 * u + 1], ka[4 * u + 2], ka[4 * u + 3]);
  }
}

// ---- k_qk2: combine 4 partials + bias -> qT,kT[b,n,32] ----
__global__ __launch_bounds__(256) void k_qk2(
    const float* __restrict__ qp, const float* __restrict__ kp,
    const float* __restrict__ bq, const float* __restrict__ bk,
    float* __restrict__ qT, float* __restrict__ kT) {
  int t = blockIdx.x * 256 + threadIdx.x;    // b*N + n, 8192 total
  int b = t >> 12, n = t & (N_ - 1);
  float qa[QK_], ka[QK_];
#pragma unroll
  for (int o = 0; o < QK_; o++) { qa[o] = bq[o]; ka[o] = bk[o]; }
#pragma unroll
  for (int cg = 0; cg < 4; cg++) {
    const float4* qs = (const float4*)(qp + (((size_t)cg * B_ + b) * N_ + n) * QK_);
    const float4* ks = (const float4*)(kp + (((size_t)cg * B_ + b) * N_ + n) * QK_);
#pragma unroll
    for (int u = 0; u < 8; u++) {
      float4 q4 = qs[u], k4 = ks[u];
      qa[4 * u] += q4.x; qa[4 * u + 1] += q4.y; qa[4 * u + 2] += q4.z; qa[4 * u + 3] += q4.w;
      ka[4 * u] += k4.x; ka[4 * u + 1] += k4.y; ka[4 * u + 2] += k4.z; ka[4 * u + 3] += k4.w;
    }
  }
  float4* qo = (float4*)(qT + ((size_t)b * N_ + n) * QK_);
  float4* ko = (float4*)(kT + ((size_t)b * N_ + n) * QK_);
#pragma unroll
  for (int u = 0; u < 8; u++) {
    qo[u] = make_float4(qa[4 * u], qa[4 * u + 1], qa[4 * u + 2], qa[4 * u + 3]);
    ko[u] = make_float4(ka[4 * u], ka[4 * u + 1], ka[4 * u + 2], ka[4 * u + 3]);
  }
}

// ---- k_vbf: V proj -> vbf[b,c,j] in bf16 ----
__global__ __launch_bounds__(256) void k_vbf(
    const float* __restrict__ x, const float* __restrict__ wv, const float* __restrict__ bv,
    bf16* __restrict__ vbf) {
  int b = blockIdx.z;
  int co0 = blockIdx.y * 32;
  int n0 = blockIdx.x * 256;
  int tid = threadIdx.x;
  float acc[32];
#pragma unroll
  for (int o = 0; o < 32; o++) acc[o] = bv[co0 + o];
  const float* xp = x + (size_t)b * C_ * N_ + n0 + tid;
  for (int c = 0; c < C_; c++) {
    float xv = xp[(size_t)c * N_];
#pragma unroll
    for (int o = 0; o < 32; o++) acc[o] += wv[(co0 + o) * C_ + c] * xv;
  }
  __shared__ float vs[256 * 33];
#pragma unroll
  for (int o = 0; o < 32; o++) vs[tid * 33 + o] = acc[o];
  __syncthreads();
#pragma unroll
  for (int o = 0; o < 32; o++)
    vbf[((size_t)b * C_ + co0 + o) * N_ + n0 + tid] = __float2bfloat16(vs[tid * 33 + o]);
}

// ---- k_pa: PAM pass A — JC_ chunks of N_/JC_ j's, online (m,l), fp32 ----
__global__ __launch_bounds__(256) void k_pa(
    const float* __restrict__ qT, const float* __restrict__ kT,
    float* __restrict__ pm, float* __restrict__ pl) {
  int b = blockIdx.z;
  int jc = blockIdx.y;                       // JC_ chunks of 256 j's
  int i = blockIdx.x * 256 + threadIdx.x;
  float q[QK_];
  const float4* qp = (const float4*)(qT + ((size_t)b * N_ + i) * QK_);
#pragma unroll
  for (int u = 0; u < 8; u++) {
    float4 t = qp[u];
    q[4 * u] = t.x; q[4 * u + 1] = t.y; q[4 * u + 2] = t.z; q[4 * u + 3] = t.w;
  }
  __shared__ float kl[64 * QK_];
  float m = -1e30f, l = 0.f;
  int j0 = jc * (N_ / JC_);
  for (int jt = 0; jt < N_ / JC_; jt += 64) {
    __syncthreads();
    const float4* src = (const float4*)(kT + ((size_t)b * N_ + j0 + jt) * QK_);
    float4* d = (float4*)kl;
    d[threadIdx.x] = src[threadIdx.x];
    d[threadIdx.x + 256] = src[threadIdx.x + 256];
    __syncthreads();
#pragma unroll 2
    for (int j = 0; j < 64; j++) {
      const float4* kv = (const float4*)(kl + j * QK_);
      float s = 0.f;
#pragma unroll
      for (int u = 0; u < 8; u++) {
        float4 t = kv[u];
        s += q[4 * u] * t.x + q[4 * u + 1] * t.y + q[4 * u + 2] * t.z + q[4 * u + 3] * t.w;
      }
      float nm = fmaxf(m, s);
      l = l * __expf(m - nm) + __expf(s - nm);
      m = nm;
    }
  }
  pm[((size_t)b * JC_ + jc) * N_ + i] = m;
  pl[((size_t)b * JC_ + jc) * N_ + i] = l;
}

// ---- k_comb: merge pass-A partials -> mrow, 1/l ----
__global__ __launch_bounds__(256) void k_comb(
    const float* __restrict__ pm, const float* __restrict__ pl,
    float* __restrict__ mrow, float* __restrict__ lrowi) {
  int t = blockIdx.x * 256 + threadIdx.x;
  int b = t >> 12, i = t & (N_ - 1);
  float M = -1e30f;
  float pmv[JC_];
#pragma unroll
  for (int c = 0; c < JC_; c++) {
    pmv[c] = pm[((size_t)b * JC_ + c) * N_ + i];
    M = fmaxf(M, pmv[c]);
  }
  float L = 0.f;
#pragma unroll
  for (int c = 0; c < JC_; c++) L += pl[((size_t)b * JC_ + c) * N_ + i] * __expf(pmv[c] - M);
  mrow[t] = M;
  lrowi[t] = 1.0f / L;
}

// ---- k_pbm v3: pamT[b,i,c] = sum_j P(i,j) V[j,c], all-MFMA, 1 barrier/iter ----
// (unchanged from R13 — race-free by construction, tripwire-validated)
__global__ __launch_bounds__(256) void k_pbm(
    const float* __restrict__ qT, const float* __restrict__ kT, const bf16* __restrict__ vbf,
    const float* __restrict__ mrow, const float* __restrict__ lrowi,
    float* __restrict__ pamT) {
  int b = blockIdx.z;
  int cb0 = blockIdx.y * CH_;
  int i0 = blockIdx.x * TI_;
  int tid = threadIdx.x;
  int lane = tid & 63, wave = tid >> 6;
  int n16 = lane & 15, quad = lane >> 4;

  __shared__ __align__(16) bf16 q_hi[32 * KP_], q_lo[32 * KP_];
  __shared__ __align__(16) bf16 k_hi[64 * KP_], k_lo[64 * KP_];
  __shared__ __align__(16) bf16 v_s[128 * VP_];
  __shared__ __align__(16) bf16 p_s[2][32 * PP_];   // double-buffered (cross-wave)

  float mreg[8], lireg[8];
#pragma unroll
  for (int ih = 0; ih < 2; ih++)
#pragma unroll
    for (int r = 0; r < 4; r++) {
      int i = ih * 16 + quad * 4 + r;
      mreg[ih * 4 + r] = mrow[b * N_ + i0 + i];
      lireg[ih * 4 + r] = lrowi[b * N_ + i0 + i];
    }

  if (tid < 128) {
    int ir = tid >> 2, kq = (tid & 3) * 8;
    const float4* qs4 = (const float4*)(qT + ((size_t)b * N_ + i0 + ir) * QK_ + kq);
    float4 f0 = qs4[0], f1 = qs4[1];
    float f[8] = {f0.x, f0.y, f0.z, f0.w, f1.x, f1.y, f1.z, f1.w};
    bf8pack uh, ul;
#pragma unroll
    for (int u = 0; u < 8; u++) {
      bf16 h = __float2bfloat16(f[u]);
      uh.h[u] = h;
      ul.h[u] = __float2bfloat16(f[u] - __bfloat162float(h));
    }
    *(int4*)(q_hi + ir * KP_ + kq) = uh.v;
    *(int4*)(q_lo + ir * KP_ + kq) = ul.v;
  }

  f32x4 acc[2][2];
#pragma unroll
  for (int ih = 0; ih < 2; ih++)
#pragma unroll
    for (int cb = 0; cb < 2; cb++) acc[ih][cb] = (f32x4)(0.f);

  int jr = tid >> 2, kq = (tid & 3) * 8;
  int vc = tid >> 1, vjh = (tid & 1) * 32;

  float4 kf0, kf1;
  int4 vf0, vf1, vf2, vf3;
  {
    const float4* ks4 = (const float4*)(kT + ((size_t)b * N_ + jr) * QK_ + kq);
    kf0 = ks4[0]; kf1 = ks4[1];
    const int4* vs4 = (const int4*)(vbf + ((size_t)b * C_ + cb0 + vc) * N_ + vjh);
    vf0 = vs4[0]; vf1 = vs4[1]; vf2 = vs4[2]; vf3 = vs4[3];
  }

  __syncthreads();   // Q visible to all waves

  for (int jt = 0; jt < N_ / TJ_; jt++) {
    {
      float f[8] = {kf0.x, kf0.y, kf0.z, kf0.w, kf1.x, kf1.y, kf1.z, kf1.w};
      bf8pack uh, ul;
#pragma unroll
      for (int u = 0; u < 8; u++) {
        bf16 h = __float2bfloat16(f[u]);
        uh.h[u] = h;
        ul.h[u] = __float2bfloat16(f[u] - __bfloat162float(h));
      }
      *(int4*)(k_hi + jr * KP_ + kq) = uh.v;
      *(int4*)(k_lo + jr * KP_ + kq) = ul.v;
      int4* vd = (int4*)(v_s + vc * VP_ + vjh);
      vd[0] = vf0; vd[1] = vf1; vd[2] = vf2; vd[3] = vf3;
    }
    if (jt + 1 < N_ / TJ_) {
      int j0n = (jt + 1) * TJ_;
      const float4* ks4 = (const float4*)(kT + ((size_t)b * N_ + j0n + jr) * QK_ + kq);
      kf0 = ks4[0]; kf1 = ks4[1];
      const int4* vs4 = (const int4*)(vbf + ((size_t)b * C_ + cb0 + vc) * N_ + j0n + vjh);
      vf0 = vs4[0]; vf1 = vs4[1]; vf2 = vs4[2]; vf3 = vs4[3];
    }
    f32x4 s[2];
    {
      bf16x8f bh = *(const bf16x8f*)(const void*)(k_hi + (wave * 16 + n16) * KP_ + quad * 8);
      bf16x8f bl = *(const bf16x8f*)(const void*)(k_lo + (wave * 16 + n16) * KP_ + quad * 8);
#pragma unroll
      for (int ih = 0; ih < 2; ih++) {
        bf16x8f ah = *(const bf16x8f*)(const void*)(q_hi + (ih * 16 + n16) * KP_ + quad * 8);
        bf16x8f al = *(const bf16x8f*)(const void*)(q_lo + (ih * 16 + n16) * KP_ + quad * 8);
        f32x4 z = (f32x4)(0.f);
        z = __builtin_amdgcn_mfma_f32_16x16x32_bf16(ah, bh, z, 0, 0, 0);
        z = __builtin_amdgcn_mfma_f32_16x16x32_bf16(al, bh, z, 0, 0, 0);
        z = __builtin_amdgcn_mfma_f32_16x16x32_bf16(ah, bl, z, 0, 0, 0);
        s[ih] = z;
      }
    }
    bf16* pbuf = p_s[jt & 1];
#pragma unroll
    for (int ih = 0; ih < 2; ih++)
#pragma unroll
      for (int r = 0; r < 4; r++) {
        int i = ih * 16 + quad * 4 + r;
        float p = __expf(s[ih][r] - mreg[ih * 4 + r]) * lireg[ih * 4 + r];
        pbuf[i * PP_ + wave * 16 + n16] = __float2bfloat16(p);
      }
    __syncthreads();   // the ONE barrier per iter
    bf16x8f pa0[2], pa1[2], vb0[2], vb1[2];
#pragma unroll
    for (int ih = 0; ih < 2; ih++) {
      pa0[ih] = *(const bf16x8f*)(const void*)(pbuf + (ih * 16 + n16) * PP_ + quad * 8);
      pa1[ih] = *(const bf16x8f*)(const void*)(pbuf + (ih * 16 + n16) * PP_ + 32 + quad * 8);
    }
#pragma unroll
    for (int cb = 0; cb < 2; cb++) {
      vb0[cb] = *(const bf16x8f*)(const void*)(v_s + (wave * 32 + cb * 16 + n16) * VP_ + quad * 8);
      vb1[cb] = *(const bf16x8f*)(const void*)(v_s + (wave * 32 + cb * 16 + n16) * VP_ + 32 + quad * 8);
    }
#pragma unroll
    for (int ih = 0; ih < 2; ih++)
#pragma unroll
      for (int cb = 0; cb < 2; cb++) {
        acc[ih][cb] = __builtin_amdgcn_mfma_f32_16x16x32_bf16(pa0[ih], vb0[cb], acc[ih][cb], 0, 0, 0);
        acc[ih][cb] = __builtin_amdgcn_mfma_f32_16x16x32_bf16(pa1[ih], vb1[cb], acc[ih][cb], 0, 0, 0);
      }
  }
#pragma unroll
  for (int ih = 0; ih < 2; ih++)
#pragma unroll
    for (int cb = 0; cb < 2; cb++) {
      int c = cb0 + wave * 32 + cb * 16 + n16;
#pragma unroll
      for (int r = 0; r < 4; r++) {
        int i = ih * 16 + quad * 4 + r;
        pamT[((size_t)b * N_ + i0 + i) * C_ + c] = acc[ih][cb][r];
      }
    }
}

// ---- k_ce: CAM energy partials over K-chunks ----
__global__ __launch_bounds__(256) void k_ce(const float* __restrict__ x, float* __restrict__ eCp) {
  int b = blockIdx.z;
  int kc = blockIdx.y;
  int it = blockIdx.x & 7, jt = blockIdx.x >> 3;
  int i0 = it * 32, j0 = jt * 32;
  __shared__ float xi[32 * 65], xj[32 * 65];
  int tid = threadIdx.x;
  int ti2 = (tid & 15) * 2, tj2 = (tid >> 4) * 2;
  float a00 = 0.f, a01 = 0.f, a10 = 0.f, a11 = 0.f;
  for (int n0 = 0; n0 < 512; n0 += 64) {
    __syncthreads();
#pragma unroll
    for (int k = 0; k < 8; k++) {
      int e = k * 256 + tid;
      int r = e >> 6, c = e & 63;
      xi[r * 65 + c] = x[((size_t)b * C_ + i0 + r) * N_ + kc * 512 + n0 + c];
      xj[r * 65 + c] = x[((size_t)b * C_ + j0 + r) * N_ + kc * 512 + n0 + c];
    }
    __syncthreads();
#pragma unroll 4
    for (int n = 0; n < 64; n++) {
      float u0 = xi[ti2 * 65 + n], u1 = xi[(ti2 + 1) * 65 + n];
      float w0 = xj[tj2 * 65 + n], w1 = xj[(tj2 + 1) * 65 + n];
      a00 += u0 * w0; a01 += u0 * w1; a10 += u1 * w0; a11 += u1 * w1;
    }
  }
  float* dst = eCp + (((size_t)kc * B_ + b) * C_ + i0) * C_ + j0;
  dst[(ti2 + 0) * C_ + tj2 + 0] = a00;
  dst[(ti2 + 0) * C_ + tj2 + 1] = a01;
  dst[(ti2 + 1) * C_ + tj2 + 0] = a10;
  dst[(ti2 + 1) * C_ + tj2 + 1] = a11;
}

// ---- k_cs: CAM softmax over -e ----
__global__ __launch_bounds__(256) void k_cs(const float* __restrict__ eCp, float* __restrict__ attnC) {
  int row = blockIdx.x;
  int b = row >> 8, i = row & 255;
  int j = threadIdx.x;
  float e = 0.f;
#pragma unroll
  for (int kc = 0; kc < 8; kc++) e += eCp[(((size_t)kc * B_ + b) * C_ + i) * C_ + j];
  float ne = -e;
  __shared__ float buf[256];
  buf[j] = ne;
  __syncthreads();
  for (int st = 128; st >= 1; st >>= 1) {
    if (j < st) buf[j] = fmaxf(buf[j], buf[j + st]);
    __syncthreads();
  }
  float m = buf[0];
  __syncthreads();
  float p = __expf(ne - m);
  buf[j] = p;
  __syncthreads();
  for (int st = 128; st >= 1; st >>= 1) {
    if (j < st) buf[j] += buf[j + st];
    __syncthreads();
  }
  attnC[(size_t)row * C_ + j] = p / buf[0];
}

// ---- k_co: CAM out + combine -> fp32 out ----
__global__ __launch_bounds__(256) void k_co(
    const float* __restrict__ x, const float* __restrict__ attnC, const float* __restrict__ pamT,
    const float* __restrict__ gpam, const float* __restrict__ gcam, float* __restrict__ out) {
  int b = blockIdx.z, c0 = blockIdx.y * 32, n0 = blockIdx.x * 256;
  int tid = threadIdx.x;
  __shared__ float pam_s[256 * 33];
#pragma unroll
  for (int k = 0; k < 32; k++) {
    int e = k * 256 + tid;
    int r = e >> 5, cc = e & 31;
    pam_s[r * 33 + cc] = pamT[((size_t)b * N_ + n0 + r) * C_ + c0 + cc];
  }
  __syncthreads();
  float acc[32];
#pragma unroll
  for (int i = 0; i < 32; i++) acc[i] = 0.f;
  const float* arow = attnC + ((size_t)b * C_ + c0) * C_;
  for (int j = 0; j < C_; j++) {
    float xv = x[((size_t)b * C_ + j) * N_ + n0 + tid];
#pragma unroll
    for (int i = 0; i < 32; i++) acc[i] += arow[i * C_ + j] * xv;
  }
  float gp = gpam[0], gc = gcam[0];
#pragma unroll
  for (int i = 0; i < 32; i++) {
    size_t idx = ((size_t)b * C_ + c0 + i) * N_ + n0 + tid;
    out[idx] = gp * pam_s[tid * 33 + i] + gc * acc[i] + 2.0f * x[idx];
  }
}

extern "C" void kernel_launch(void* const* d_in, const int* in_sizes, int n_in,
                              void* d_out, int out_size, void* d_ws, size_t ws_size,
                              hipStream_t stream) {
  const float* x  = (const float*)d_in[0];
  const float* wq = (const float*)d_in[1];
  const float* bq = (const float*)d_in[2];
  const float* wk = (const float*)d_in[3];
  const float* bk = (const float*)d_in[4];
  const float* wv = (const float*)d_in[5];
  const float* bv = (const float*)d_in[6];
  const float* gp = (const float*)d_in[7];
  const float* gc = (const float*)d_in[8];
  float* out = (float*)d_out;

  float* ws = (float*)d_ws;
  size_t o = 0;
  float* qT    = ws + o; o += (size_t)B_ * N_ * QK_;    // 262144
  float* kT    = ws + o; o += (size_t)B_ * N_ * QK_;    // 262144
  float* pamT  = ws + o; o += (size_t)B_ * N_ * C_;     // 2097152
  float* pm    = ws + o; o += (size_t)B_ * JC_ * N_;    // 131072
  float* pl    = ws + o; o += (size_t)B_ * JC_ * N_;    // 131072
  float* mrow  = ws + o; o += (size_t)B_ * N_;          // 8192
  float* lrowi = ws + o; o += (size_t)B_ * N_;          // 8192
  float* eCp   = ws + o; o += (size_t)8 * B_ * C_ * C_; // 1048576
  float* attnC = ws + o; o += (size_t)B_ * C_ * C_;     // 131072
  bf16*  vbf   = (bf16*)(ws + o); o += (size_t)B_ * N_ * C_ / 2;  // 1048576
  float* qpprt = ws + o; o += (size_t)4 * B_ * N_ * QK_; // 1048576
  float* kpprt = ws + o; o += (size_t)4 * B_ * N_ * QK_; // 1048576
  // total 7,225,344 floats = 28.9 MB (< R5-proven 32.9 MB envelope)

  k_qk1<<<dim3(16, 4, B_), dim3(256), 0, stream>>>(x, wq, wk, qpprt, kpprt);
  k_qk2<<<dim3(32), dim3(256), 0, stream>>>(qpprt, kpprt, bq, bk, qT, kT);
  k_vbf<<<dim3(16, 8, B_), dim3(256), 0, stream>>>(x, wv, bv, vbf);
  k_pa<<<dim3(16, JC_, B_), dim3(256), 0, stream>>>(qT, kT, pm, pl);
  k_comb<<<dim3(32), dim3(256), 0, stream>>>(pm, pl, mrow, lrowi);
  k_pbm<<<dim3(N_ / TI_, C_ / CH_, B_), dim3(256), 0, stream>>>(qT, kT, vbf, mrow, lrowi, pamT);
  k_ce<<<dim3(64, 8, B_), dim3(256), 0, stream>>>(x, eCp);
  k_cs<<<dim3(B_ * C_), dim3(256), 0, stream>>>(eCp, attnC);
  k_co<<<dim3(16, 8, B_), dim3(256), 0, stream>>>(x, attnC, pamT, gp, gc, out);
}

// Round 15
// 412.015 us; speedup vs baseline: 7.4950x; 1.0488x over previous
//
#include <hip/hip_runtime.h>
#include <hip/hip_bf16.h>

// DA block (DANet) — Round 15: ILP fixes.
//  - k_pa v2 (86.7us, VALUBusy 72%, serial 32-FMA chain): 8-wide j-blocking ->
//    8 independent accumulators (ILP 8), group-max softmax update (1.13 exp/j vs 2).
//  - k_vbf: remove no-op LDS roundtrip; channel-split 32->8/block (grid x4).
//  - k_pbm v3 (race-free), k_qk1/2, CAM trio unchanged (R14-green).
// Inputs fp32 dict order; output fp32.

#define B_ 2
#define C_ 256
#define N_ 4096
#define QK_ 32
#define JC_ 16     // k_pa j-chunks

#define TI_ 32     // k_pbm i-rows per block
#define TJ_ 64     // k_pbm j per tile
#define CH_ 128    // k_pbm channels per block
#define KP_ 40     // k/q LDS pitch (bf16) = 80 B (16-aligned)
#define VP_ 72     // v LDS pitch (bf16) = 144 B
#define PP_ 72     // p LDS pitch (bf16) = 144 B

typedef __hip_bfloat16 bf16;
typedef __attribute__((ext_vector_type(8))) short bf16x8f;   // MFMA A/B frag
typedef __attribute__((ext_vector_type(4))) float f32x4;     // MFMA C/D frag

union bf8pack { bf16 h[8]; int4 v; };

// ---- k_qk1: partial Q,K projections over a 64-channel chunk ----
__global__ __launch_bounds__(256) void k_qk1(
    const float* __restrict__ x, const float* __restrict__ wq, const float* __restrict__ wk,
    float* __restrict__ qp, float* __restrict__ kp) {
  int b = blockIdx.z;
  int cg = blockIdx.y;                      // 4 chunks of 64 channels
  int n = blockIdx.x * 256 + threadIdx.x;
  float qa[QK_], ka[QK_];
#pragma unroll
  for (int o = 0; o < QK_; o++) { qa[o] = 0.f; ka[o] = 0.f; }
  const float* xp = x + ((size_t)b * C_ + cg * 64) * N_ + n;
  for (int c = 0; c < 64; c++) {
    float xv = xp[(size_t)c * N_];
    int cc = cg * 64 + c;
#pragma unroll
    for (int o = 0; o < QK_; o++) {
      qa[o] += wq[o * C_ + cc] * xv;   // uniform weight loads -> scalar path
      ka[o] += wk[o * C_ + cc] * xv;
    }
  }
  float4* qo = (float4*)(qp + (((size_t)cg * B_ + b) * N_ + n) * QK_);
  float4* ko = (float4*)(kp + (((size_t)cg * B_ + b) * N_ + n) * QK_);
#pragma unroll
  for (int u = 0; u < 8; u++) {
    qo[u] = make_float4(qa[4 * u], qa[4 * u + 1], qa[4 * u + 2], qa[4 * u + 3]);
    ko[u] = make_float4(ka[4 * u], ka[4 * u + 1], ka[4 * u + 2], ka[4 * u + 3]);
  }
}

// ---- k_qk2: combine 4 partials + bias -> qT,kT[b,n,32] ----
__global__ __launch_bounds__(256) void k_qk2(
    const float* __restrict__ qp, const float* __restrict__ kp,
    const float* __restrict__ bq, const float* __restrict__ bk,
    float* __restrict__ qT, float* __restrict__ kT) {
  int t = blockIdx.x * 256 + threadIdx.x;    // b*N + n
  int b = t >> 12, n = t & (N_ - 1);
  float qa[QK_], ka[QK_];
#pragma unroll
  for (int o = 0; o < QK_; o++) { qa[o] = bq[o]; ka[o] = bk[o]; }
#pragma unroll
  for (int cg = 0; cg < 4; cg++) {
    const float4* qs = (const float4*)(qp + (((size_t)cg * B_ + b) * N_ + n) * QK_);
    const float4* ks = (const float4*)(kp + (((size_t)cg * B_ + b) * N_ + n) * QK_);
#pragma unroll
    for (int u = 0; u < 8; u++) {
      float4 q4 = qs[u], k4 = ks[u];
      qa[4 * u] += q4.x; qa[4 * u + 1] += q4.y; qa[4 * u + 2] += q4.z; qa[4 * u + 3] += q4.w;
      ka[4 * u] += k4.x; ka[4 * u + 1] += k4.y; ka[4 * u + 2] += k4.z; ka[4 * u + 3] += k4.w;
    }
  }
  float4* qo = (float4*)(qT + ((size_t)b * N_ + n) * QK_);
  float4* ko = (float4*)(kT + ((size_t)b * N_ + n) * QK_);
#pragma unroll
  for (int u = 0; u < 8; u++) {
    qo[u] = make_float4(qa[4 * u], qa[4 * u + 1], qa[4 * u + 2], qa[4 * u + 3]);
    ko[u] = make_float4(ka[4 * u], ka[4 * u + 1], ka[4 * u + 2], ka[4 * u + 3]);
  }
}

// ---- k_vbf v2: V proj -> vbf[b,c,j] bf16; 8 channels/block, no LDS ----
__global__ __launch_bounds__(256) void k_vbf(
    const float* __restrict__ x, const float* __restrict__ wv, const float* __restrict__ bv,
    bf16* __restrict__ vbf) {
  int b = blockIdx.z;
  int co0 = blockIdx.y * 8;
  int n0 = blockIdx.x * 256;
  int tid = threadIdx.x;
  float acc[8];
#pragma unroll
  for (int o = 0; o < 8; o++) acc[o] = bv[co0 + o];
  const float* xp = x + (size_t)b * C_ * N_ + n0 + tid;
  for (int c = 0; c < C_; c++) {
    float xv = xp[(size_t)c * N_];
#pragma unroll
    for (int o = 0; o < 8; o++) acc[o] += wv[(co0 + o) * C_ + c] * xv;
  }
#pragma unroll
  for (int o = 0; o < 8; o++)
    vbf[((size_t)b * C_ + co0 + o) * N_ + n0 + tid] = __float2bfloat16(acc[o]);
}

// ---- k_pa v2: online (m,l) with 8-wide j-blocking (ILP 8, fewer exps) ----
__global__ __launch_bounds__(256) void k_pa(
    const float* __restrict__ qT, const float* __restrict__ kT,
    float* __restrict__ pm, float* __restrict__ pl) {
  int b = blockIdx.z;
  int jc = blockIdx.y;                       // JC_ chunks of N_/JC_ j's
  int i = blockIdx.x * 256 + threadIdx.x;
  float4 q4[8];
  {
    const float4* qp = (const float4*)(qT + ((size_t)b * N_ + i) * QK_);
#pragma unroll
    for (int u = 0; u < 8; u++) q4[u] = qp[u];
  }
  __shared__ float kl[64 * QK_];
  float m = -1e30f, l = 0.f;
  int j0 = jc * (N_ / JC_);
  for (int jt = 0; jt < N_ / JC_; jt += 64) {
    __syncthreads();
    const float4* src = (const float4*)(kT + ((size_t)b * N_ + j0 + jt) * QK_);
    float4* d = (float4*)kl;
    d[threadIdx.x] = src[threadIdx.x];
    d[threadIdx.x + 256] = src[threadIdx.x + 256];
    __syncthreads();
#pragma unroll 2
    for (int g = 0; g < 8; g++) {            // 8 groups of 8 j
      float s[8];
#pragma unroll
      for (int jj = 0; jj < 8; jj++) s[jj] = 0.f;
#pragma unroll
      for (int u = 0; u < 8; u++) {
        float4 qv = q4[u];
#pragma unroll
        for (int jj = 0; jj < 8; jj++) {     // 8 independent chains (broadcast LDS reads)
          float4 kv = *(const float4*)(kl + (g * 8 + jj) * QK_ + u * 4);
          s[jj] += qv.x * kv.x + qv.y * kv.y + qv.z * kv.z + qv.w * kv.w;
        }
      }
      float gm = s[0];
#pragma unroll
      for (int jj = 1; jj < 8; jj++) gm = fmaxf(gm, s[jj]);
      float nm = fmaxf(m, gm);
      float a = 0.f;
#pragma unroll
      for (int jj = 0; jj < 8; jj++) a += __expf(s[jj] - nm);
      l = l * __expf(m - nm) + a;
      m = nm;
    }
  }
  pm[((size_t)b * JC_ + jc) * N_ + i] = m;
  pl[((size_t)b * JC_ + jc) * N_ + i] = l;
}

// ---- k_comb: merge pass-A partials -> mrow, 1/l ----
__global__ __launch_bounds__(256) void k_comb(
    const float* __restrict__ pm, const float* __restrict__ pl,
    float* __restrict__ mrow, float* __restrict__ lrowi) {
  int t = blockIdx.x * 256 + threadIdx.x;
  int b = t >> 12, i = t & (N_ - 1);
  float M = -1e30f;
  float pmv[JC_];
#pragma unroll
  for (int c = 0; c < JC_; c++) {
    pmv[c] = pm[((size_t)b * JC_ + c) * N_ + i];
    M = fmaxf(M, pmv[c]);
  }
  float L = 0.f;
#pragma unroll
  for (int c = 0; c < JC_; c++) L += pl[((size_t)b * JC_ + c) * N_ + i] * __expf(pmv[c] - M);
  mrow[t] = M;
  lrowi[t] = 1.0f / L;
}

// ---- k_pbm v3: pamT[b,i,c] = sum_j P(i,j) V[j,c], all-MFMA, 1 barrier/iter ----
// (unchanged from R13 — race-free by construction, tripwire-validated)
__global__ __launch_bounds__(256) void k_pbm(
    const float* __restrict__ qT, const float* __restrict__ kT, const bf16* __restrict__ vbf,
    const float* __restrict__ mrow, const float* __restrict__ lrowi,
    float* __restrict__ pamT) {
  int b = blockIdx.z;
  int cb0 = blockIdx.y * CH_;
  int i0 = blockIdx.x * TI_;
  int tid = threadIdx.x;
  int lane = tid & 63, wave = tid >> 6;
  int n16 = lane & 15, quad = lane >> 4;

  __shared__ __align__(16) bf16 q_hi[32 * KP_], q_lo[32 * KP_];
  __shared__ __align__(16) bf16 k_hi[64 * KP_], k_lo[64 * KP_];
  __shared__ __align__(16) bf16 v_s[128 * VP_];
  __shared__ __align__(16) bf16 p_s[2][32 * PP_];   // double-buffered (cross-wave)

  float mreg[8], lireg[8];
#pragma unroll
  for (int ih = 0; ih < 2; ih++)
#pragma unroll
    for (int r = 0; r < 4; r++) {
      int i = ih * 16 + quad * 4 + r;
      mreg[ih * 4 + r] = mrow[b * N_ + i0 + i];
      lireg[ih * 4 + r] = lrowi[b * N_ + i0 + i];
    }

  if (tid < 128) {
    int ir = tid >> 2, kq = (tid & 3) * 8;
    const float4* qs4 = (const float4*)(qT + ((size_t)b * N_ + i0 + ir) * QK_ + kq);
    float4 f0 = qs4[0], f1 = qs4[1];
    float f[8] = {f0.x, f0.y, f0.z, f0.w, f1.x, f1.y, f1.z, f1.w};
    bf8pack uh, ul;
#pragma unroll
    for (int u = 0; u < 8; u++) {
      bf16 h = __float2bfloat16(f[u]);
      uh.h[u] = h;
      ul.h[u] = __float2bfloat16(f[u] - __bfloat162float(h));
    }
    *(int4*)(q_hi + ir * KP_ + kq) = uh.v;
    *(int4*)(q_lo + ir * KP_ + kq) = ul.v;
  }

  f32x4 acc[2][2];
#pragma unroll
  for (int ih = 0; ih < 2; ih++)
#pragma unroll
    for (int cb = 0; cb < 2; cb++) acc[ih][cb] = (f32x4)(0.f);

  int jr = tid >> 2, kq = (tid & 3) * 8;
  int vc = tid >> 1, vjh = (tid & 1) * 32;

  float4 kf0, kf1;
  int4 vf0, vf1, vf2, vf3;
  {
    const float4* ks4 = (const float4*)(kT + ((size_t)b * N_ + jr) * QK_ + kq);
    kf0 = ks4[0]; kf1 = ks4[1];
    const int4* vs4 = (const int4*)(vbf + ((size_t)b * C_ + cb0 + vc) * N_ + vjh);
    vf0 = vs4[0]; vf1 = vs4[1]; vf2 = vs4[2]; vf3 = vs4[3];
  }

  __syncthreads();   // Q visible to all waves

  for (int jt = 0; jt < N_ / TJ_; jt++) {
    {
      float f[8] = {kf0.x, kf0.y, kf0.z, kf0.w, kf1.x, kf1.y, kf1.z, kf1.w};
      bf8pack uh, ul;
#pragma unroll
      for (int u = 0; u < 8; u++) {
        bf16 h = __float2bfloat16(f[u]);
        uh.h[u] = h;
        ul.h[u] = __float2bfloat16(f[u] - __bfloat162float(h));
      }
      *(int4*)(k_hi + jr * KP_ + kq) = uh.v;
      *(int4*)(k_lo + jr * KP_ + kq) = ul.v;
      int4* vd = (int4*)(v_s + vc * VP_ + vjh);
      vd[0] = vf0; vd[1] = vf1; vd[2] = vf2; vd[3] = vf3;
    }
    if (jt + 1 < N_ / TJ_) {
      int j0n = (jt + 1) * TJ_;
      const float4* ks4 = (const float4*)(kT + ((size_t)b * N_ + j0n + jr) * QK_ + kq);
      kf0 = ks4[0]; kf1 = ks4[1];
      const int4* vs4 = (const int4*)(vbf + ((size_t)b * C_ + cb0 + vc) * N_ + j0n + vjh);
      vf0 = vs4[0]; vf1 = vs4[1]; vf2 = vs4[2]; vf3 = vs4[3];
    }
    f32x4 s[2];
    {
      bf16x8f bh = *(const bf16x8f*)(const void*)(k_hi + (wave * 16 + n16) * KP_ + quad * 8);
      bf16x8f bl = *(const bf16x8f*)(const void*)(k_lo + (wave * 16 + n16) * KP_ + quad * 8);
#pragma unroll
      for (int ih = 0; ih < 2; ih++) {
        bf16x8f ah = *(const bf16x8f*)(const void*)(q_hi + (ih * 16 + n16) * KP_ + quad * 8);
        bf16x8f al = *(const bf16x8f*)(const void*)(q_lo + (ih * 16 + n16) * KP_ + quad * 8);
        f32x4 z = (f32x4)(0.f);
        z = __builtin_amdgcn_mfma_f32_16x16x32_bf16(ah, bh, z, 0, 0, 0);
        z = __builtin_amdgcn_mfma_f32_16x16x32_bf16(al, bh, z, 0, 0, 0);
        z = __builtin_amdgcn_mfma_f32_16x16x32_bf16(ah, bl, z, 0, 0, 0);
        s[ih] = z;
      }
    }
    bf16* pbuf = p_s[jt & 1];
#pragma unroll
    for (int ih = 0; ih < 2; ih++)
#pragma unroll
      for (int r = 0; r < 4; r++) {
        int i = ih * 16 + quad * 4 + r;
        float p = __expf(s[ih][r] - mreg[ih * 4 + r]) * lireg[ih * 4 + r];
        pbuf[i * PP_ + wave * 16 + n16] = __float2bfloat16(p);
      }
    __syncthreads();   // the ONE barrier per iter
    bf16x8f pa0[2], pa1[2], vb0[2], vb1[2];
#pragma unroll
    for (int ih = 0; ih < 2; ih++) {
      pa0[ih] = *(const bf16x8f*)(const void*)(pbuf + (ih * 16 + n16) * PP_ + quad * 8);
      pa1[ih] = *(const bf16x8f*)(const void*)(pbuf + (ih * 16 + n16) * PP_ + 32 + quad * 8);
    }
#pragma unroll
    for (int cb = 0; cb < 2; cb++) {
      vb0[cb] = *(const bf16x8f*)(const void*)(v_s + (wave * 32 + cb * 16 + n16) * VP_ + quad * 8);
      vb1[cb] = *(const bf16x8f*)(const void*)(v_s + (wave * 32 + cb * 16 + n16) * VP_ + 32 + quad * 8);
    }
#pragma unroll
    for (int ih = 0; ih < 2; ih++)
#pragma unroll
      for (int cb = 0; cb < 2; cb++) {
        acc[ih][cb] = __builtin_amdgcn_mfma_f32_16x16x32_bf16(pa0[ih], vb0[cb], acc[ih][cb], 0, 0, 0);
        acc[ih][cb] = __builtin_amdgcn_mfma_f32_16x16x32_bf16(pa1[ih], vb1[cb], acc[ih][cb], 0, 0, 0);
      }
  }
#pragma unroll
  for (int ih = 0; ih < 2; ih++)
#pragma unroll
    for (int cb = 0; cb < 2; cb++) {
      int c = cb0 + wave * 32 + cb * 16 + n16;
#pragma unroll
      for (int r = 0; r < 4; r++) {
        int i = ih * 16 + quad * 4 + r;
        pamT[((size_t)b * N_ + i0 + i) * C_ + c] = acc[ih][cb][r];
      }
    }
}

// ---- k_ce: CAM energy partials over K-chunks ----
__global__ __launch_bounds__(256) void k_ce(const float* __restrict__ x, float* __restrict__ eCp) {
  int b = blockIdx.z;
  int kc = blockIdx.y;
  int it = blockIdx.x & 7, jt = blockIdx.x >> 3;
  int i0 = it * 32, j0 = jt * 32;
  __shared__ float xi[32 * 65], xj[32 * 65];
  int tid = threadIdx.x;
  int ti2 = (tid & 15) * 2, tj2 = (tid >> 4) * 2;
  float a00 = 0.f, a01 = 0.f, a10 = 0.f, a11 = 0.f;
  for (int n0 = 0; n0 < 512; n0 += 64) {
    __syncthreads();
#pragma unroll
    for (int k = 0; k < 8; k++) {
      int e = k * 256 + tid;
      int r = e >> 6, c = e & 63;
      xi[r * 65 + c] = x[((size_t)b * C_ + i0 + r) * N_ + kc * 512 + n0 + c];
      xj[r * 65 + c] = x[((size_t)b * C_ + j0 + r) * N_ + kc * 512 + n0 + c];
    }
    __syncthreads();
#pragma unroll 4
    for (int n = 0; n < 64; n++) {
      float u0 = xi[ti2 * 65 + n], u1 = xi[(ti2 + 1) * 65 + n];
      float w0 = xj[tj2 * 65 + n], w1 = xj[(tj2 + 1) * 65 + n];
      a00 += u0 * w0; a01 += u0 * w1; a10 += u1 * w0; a11 += u1 * w1;
    }
  }
  float* dst = eCp + (((size_t)kc * B_ + b) * C_ + i0) * C_ + j0;
  dst[(ti2 + 0) * C_ + tj2 + 0] = a00;
  dst[(ti2 + 0) * C_ + tj2 + 1] = a01;
  dst[(ti2 + 1) * C_ + tj2 + 0] = a10;
  dst[(ti2 + 1) * C_ + tj2 + 1] = a11;
}

// ---- k_cs: CAM softmax over -e ----
__global__ __launch_bounds__(256) void k_cs(const float* __restrict__ eCp, float* __restrict__ attnC) {
  int row = blockIdx.x;
  int b = row >> 8, i = row & 255;
  int j = threadIdx.x;
  float e = 0.f;
#pragma unroll
  for (int kc = 0; kc < 8; kc++) e += eCp[(((size_t)kc * B_ + b) * C_ + i) * C_ + j];
  float ne = -e;
  __shared__ float buf[256];
  buf[j] = ne;
  __syncthreads();
  for (int st = 128; st >= 1; st >>= 1) {
    if (j < st) buf[j] = fmaxf(buf[j], buf[j + st]);
    __syncthreads();
  }
  float m = buf[0];
  __syncthreads();
  float p = __expf(ne - m);
  buf[j] = p;
  __syncthreads();
  for (int st = 128; st >= 1; st >>= 1) {
    if (j < st) buf[j] += buf[j + st];
    __syncthreads();
  }
  attnC[(size_t)row * C_ + j] = p / buf[0];
}

// ---- k_co: CAM out + combine -> fp32 out ----
__global__ __launch_bounds__(256) void k_co(
    const float* __restrict__ x, const float* __restrict__ attnC, const float* __restrict__ pamT,
    const float* __restrict__ gpam, const float* __restrict__ gcam, float* __restrict__ out) {
  int b = blockIdx.z, c0 = blockIdx.y * 32, n0 = blockIdx.x * 256;
  int tid = threadIdx.x;
  __shared__ float pam_s[256 * 33];
#pragma unroll
  for (int k = 0; k < 32; k++) {
    int e = k * 256 + tid;
    int r = e >> 5, cc = e & 31;
    pam_s[r * 33 + cc] = pamT[((size_t)b * N_ + n0 + r) * C_ + c0 + cc];
  }
  __syncthreads();
  float acc[32];
#pragma unroll
  for (int i = 0; i < 32; i++) acc[i] = 0.f;
  const float* arow = attnC + ((size_t)b * C_ + c0) * C_;
  for (int j = 0; j < C_; j++) {
    float xv = x[((size_t)b * C_ + j) * N_ + n0 + tid];
#pragma unroll
    for (int i = 0; i < 32; i++) acc[i] += arow[i * C_ + j] * xv;
  }
  float gp = gpam[0], gc = gcam[0];
#pragma unroll
  for (int i = 0; i < 32; i++) {
    size_t idx = ((size_t)b * C_ + c0 + i) * N_ + n0 + tid;
    out[idx] = gp * pam_s[tid * 33 + i] + gc * acc[i] + 2.0f * x[idx];
  }
}

extern "C" void kernel_launch(void* const* d_in, const int* in_sizes, int n_in,
                              void* d_out, int out_size, void* d_ws, size_t ws_size,
                              hipStream_t stream) {
  const float* x  = (const float*)d_in[0];
  const float* wq = (const float*)d_in[1];
  const float* bq = (const float*)d_in[2];
  const float* wk = (const float*)d_in[3];
  const float* bk = (const float*)d_in[4];
  const float* wv = (const float*)d_in[5];
  const float* bv = (const float*)d_in[6];
  const float* gp = (const float*)d_in[7];
  const float* gc = (const float*)d_in[8];
  float* out = (float*)d_out;

  float* ws = (float*)d_ws;
  size_t o = 0;
  float* qT    = ws + o; o += (size_t)B_ * N_ * QK_;    // 262144
  float* kT    = ws + o; o += (size_t)B_ * N_ * QK_;    // 262144
  float* pamT  = ws + o; o += (size_t)B_ * N_ * C_;     // 2097152
  float* pm    = ws + o; o += (size_t)B_ * JC_ * N_;    // 131072
  float* pl    = ws + o; o += (size_t)B_ * JC_ * N_;    // 131072
  float* mrow  = ws + o; o += (size_t)B_ * N_;          // 8192
  float* lrowi = ws + o; o += (size_t)B_ * N_;          // 8192
  float* eCp   = ws + o; o += (size_t)8 * B_ * C_ * C_; // 1048576
  float* attnC = ws + o; o += (size_t)B_ * C_ * C_;     // 131072
  bf16*  vbf   = (bf16*)(ws + o); o += (size_t)B_ * N_ * C_ / 2;  // 1048576
  float* qpprt = ws + o; o += (size_t)4 * B_ * N_ * QK_; // 1048576
  float* kpprt = ws + o; o += (size_t)4 * B_ * N_ * QK_; // 1048576
  // total 7,225,344 floats = 28.9 MB

  k_qk1<<<dim3(16, 4, B_), dim3(256), 0, stream>>>(x, wq, wk, qpprt, kpprt);
  k_qk2<<<dim3(32), dim3(256), 0, stream>>>(qpprt, kpprt, bq, bk, qT, kT);
  k_vbf<<<dim3(16, 32, B_), dim3(256), 0, stream>>>(x, wv, bv, vbf);
  k_pa<<<dim3(16, JC_, B_), dim3(256), 0, stream>>>(qT, kT, pm, pl);
  k_comb<<<dim3(32), dim3(256), 0, stream>>>(pm, pl, mrow, lrowi);
  k_pbm<<<dim3(N_ / TI_, C_ / CH_, B_), dim3(256), 0, stream>>>(qT, kT, vbf, mrow, lrowi, pamT);
  k_ce<<<dim3(64, 8, B_), dim3(256), 0, stream>>>(x, eCp);
  k_cs<<<dim3(B_ * C_), dim3(256), 0, stream>>>(eCp, attnC);
  k_co<<<dim3(16, 8, B_), dim3(256), 0, stream>>>(x, attnC, pamT, gp, gc, out);
}

// Round 16
// 356.228 us; speedup vs baseline: 8.6687x; 1.1566x over previous
//
#include <hip/hip_runtime.h>
#include <hip/hip_bf16.h>

// DA block (DANet) — Round 16: k_pa was LDS-read-throughput-bound (8 ds_read_b128
// per j per wave ≈ 82 us of LDS port time — matches 86-88 us measured, and why
// R15's ILP change was flat). Replace k_pa+k_comb with k_pam2: MFMA pass A with
// DIRECT GLOBAL K fragments (no LDS for K, no loop barriers), per-lane online
// (m,l), shfl-xor merge, writes mrow/lrowi directly.
// Also: hoist loop-invariant Q-fragment LDS reads in k_pbm.
// Inputs fp32 dict order; output fp32.

#define B_ 2
#define C_ 256
#define N_ 4096
#define QK_ 32

#define TI_ 32     // i-rows per block (pass A & B)
#define TJ_ 64     // j per tile
#define CH_ 128    // k_pbm channels per block
#define KP_ 40     // k/q LDS pitch (bf16) = 80 B (16-aligned)
#define VP_ 72     // v LDS pitch (bf16) = 144 B
#define PP_ 72     // p LDS pitch (bf16) = 144 B

typedef __hip_bfloat16 bf16;
typedef __attribute__((ext_vector_type(8))) short bf16x8f;   // MFMA A/B frag
typedef __attribute__((ext_vector_type(4))) float f32x4;     // MFMA C/D frag

union bf8pack { bf16 h[8]; int4 v; bf16x8f f; };

// ---- k_qk1: partial Q,K projections over a 64-channel chunk ----
__global__ __launch_bounds__(256) void k_qk1(
    const float* __restrict__ x, const float* __restrict__ wq, const float* __restrict__ wk,
    float* __restrict__ qp, float* __restrict__ kp) {
  int b = blockIdx.z;
  int cg = blockIdx.y;                      // 4 chunks of 64 channels
  int n = blockIdx.x * 256 + threadIdx.x;
  float qa[QK_], ka[QK_];
#pragma unroll
  for (int o = 0; o < QK_; o++) { qa[o] = 0.f; ka[o] = 0.f; }
  const float* xp = x + ((size_t)b * C_ + cg * 64) * N_ + n;
  for (int c = 0; c < 64; c++) {
    float xv = xp[(size_t)c * N_];
    int cc = cg * 64 + c;
#pragma unroll
    for (int o = 0; o < QK_; o++) {
      qa[o] += wq[o * C_ + cc] * xv;   // uniform weight loads -> scalar path
      ka[o] += wk[o * C_ + cc] * xv;
    }
  }
  float4* qo = (float4*)(qp + (((size_t)cg * B_ + b) * N_ + n) * QK_);
  float4* ko = (float4*)(kp + (((size_t)cg * B_ + b) * N_ + n) * QK_);
#pragma unroll
  for (int u = 0; u < 8; u++) {
    qo[u] = make_float4(qa[4 * u], qa[4 * u + 1], qa[4 * u + 2], qa[4 * u + 3]);
    ko[u] = make_float4(ka[4 * u], ka[4 * u + 1], ka[4 * u + 2], ka[4 * u + 3]);
  }
}

// ---- k_qk2: combine 4 partials + bias -> qT,kT[b,n,32] ----
__global__ __launch_bounds__(256) void k_qk2(
    const float* __restrict__ qp, const float* __restrict__ kp,
    const float* __restrict__ bq, const float* __restrict__ bk,
    float* __restrict__ qT, float* __restrict__ kT) {
  int t = blockIdx.x * 256 + threadIdx.x;    // b*N + n
  int b = t >> 12, n = t & (N_ - 1);
  float qa[QK_], ka[QK_];
#pragma unroll
  for (int o = 0; o < QK_; o++) { qa[o] = bq[o]; ka[o] = bk[o]; }
#pragma unroll
  for (int cg = 0; cg < 4; cg++) {
    const float4* qs = (const float4*)(qp + (((size_t)cg * B_ + b) * N_ + n) * QK_);
    const float4* ks = (const float4*)(kp + (((size_t)cg * B_ + b) * N_ + n) * QK_);
#pragma unroll
    for (int u = 0; u < 8; u++) {
      float4 q4 = qs[u], k4 = ks[u];
      qa[4 * u] += q4.x; qa[4 * u + 1] += q4.y; qa[4 * u + 2] += q4.z; qa[4 * u + 3] += q4.w;
      ka[4 * u] += k4.x; ka[4 * u + 1] += k4.y; ka[4 * u + 2] += k4.z; ka[4 * u + 3] += k4.w;
    }
  }
  float4* qo = (float4*)(qT + ((size_t)b * N_ + n) * QK_);
  float4* ko = (float4*)(kT + ((size_t)b * N_ + n) * QK_);
#pragma unroll
  for (int u = 0; u < 8; u++) {
    qo[u] = make_float4(qa[4 * u], qa[4 * u + 1], qa[4 * u + 2], qa[4 * u + 3]);
    ko[u] = make_float4(ka[4 * u], ka[4 * u + 1], ka[4 * u + 2], ka[4 * u + 3]);
  }
}

// ---- k_vbf: V proj -> vbf[b,c,j] bf16; 8 channels/block ----
__global__ __launch_bounds__(256) void k_vbf(
    const float* __restrict__ x, const float* __restrict__ wv, const float* __restrict__ bv,
    bf16* __restrict__ vbf) {
  int b = blockIdx.z;
  int co0 = blockIdx.y * 8;
  int n0 = blockIdx.x * 256;
  int tid = threadIdx.x;
  float acc[8];
#pragma unroll
  for (int o = 0; o < 8; o++) acc[o] = bv[co0 + o];
  const float* xp = x + (size_t)b * C_ * N_ + n0 + tid;
  for (int c = 0; c < C_; c++) {
    float xv = xp[(size_t)c * N_];
#pragma unroll
    for (int o = 0; o < 8; o++) acc[o] += wv[(co0 + o) * C_ + c] * xv;
  }
#pragma unroll
  for (int o = 0; o < 8; o++)
    vbf[((size_t)b * C_ + co0 + o) * N_ + n0 + tid] = __float2bfloat16(acc[o]);
}

// ---- k_pam2: MFMA pass A — online (m,l) per row, direct-global K frags ----
// Block: 256 thr = 4 waves, 32 i-rows, all 4096 j. Wave w covers j = jt*64+w*16+n16.
// No LDS for K, no barriers in the loop. Writes mrow + lrowi (1/l) directly.
__global__ __launch_bounds__(256) void k_pam2(
    const float* __restrict__ qT, const float* __restrict__ kT,
    float* __restrict__ mrow, float* __restrict__ lrowi) {
  int b = blockIdx.y;
  int i0 = blockIdx.x * TI_;
  int tid = threadIdx.x;
  int lane = tid & 63, wave = tid >> 6;
  int n16 = lane & 15, quad = lane >> 4;

  __shared__ __align__(16) bf16 q_hi[32 * KP_], q_lo[32 * KP_];
  __shared__ float red_m[4 * 32], red_l[4 * 32];

  // stage Q once (32x32 fp32 -> hi/lo bf16)
  if (tid < 128) {
    int ir = tid >> 2, kq = (tid & 3) * 8;
    const float4* qs4 = (const float4*)(qT + ((size_t)b * N_ + i0 + ir) * QK_ + kq);
    float4 f0 = qs4[0], f1 = qs4[1];
    float f[8] = {f0.x, f0.y, f0.z, f0.w, f1.x, f1.y, f1.z, f1.w};
    bf8pack uh, ul;
#pragma unroll
    for (int u = 0; u < 8; u++) {
      bf16 h = __float2bfloat16(f[u]);
      uh.h[u] = h;
      ul.h[u] = __float2bfloat16(f[u] - __bfloat162float(h));
    }
    *(int4*)(q_hi + ir * KP_ + kq) = uh.v;
    *(int4*)(q_lo + ir * KP_ + kq) = ul.v;
  }
  __syncthreads();

  // hoist loop-invariant Q fragments
  bf16x8f ahf[2], alf[2];
#pragma unroll
  for (int ih = 0; ih < 2; ih++) {
    ahf[ih] = *(const bf16x8f*)(const void*)(q_hi + (ih * 16 + n16) * KP_ + quad * 8);
    alf[ih] = *(const bf16x8f*)(const void*)(q_lo + (ih * 16 + n16) * KP_ + quad * 8);
  }

  // per-lane online (m,l): 8 cells = rows {ih*16+quad*4+r} x this lane's col slice
  float m8[8], l8[8];
#pragma unroll
  for (int k = 0; k < 8; k++) { m8[k] = -3.0e38f; l8[k] = 0.f; }

  // lane's K fragment source: row wave*16+n16 (+ jt*64), cols quad*8..+8
  const float* kbase = kT + ((size_t)b * N_ + wave * 16 + n16) * QK_ + quad * 8;
  float4 kf0 = *(const float4*)(kbase);
  float4 kf1 = *(const float4*)(kbase + 4);

  for (int jt = 0; jt < N_ / TJ_; jt++) {
    // convert prefetched K to hi/lo frags (regs only)
    bf8pack kh, klo;
    {
      float f[8] = {kf0.x, kf0.y, kf0.z, kf0.w, kf1.x, kf1.y, kf1.z, kf1.w};
#pragma unroll
      for (int u = 0; u < 8; u++) {
        bf16 h = __float2bfloat16(f[u]);
        kh.h[u] = h;
        klo.h[u] = __float2bfloat16(f[u] - __bfloat162float(h));
      }
    }
    // prefetch next tile's fragment
    if (jt + 1 < N_ / TJ_) {
      const float* knext = kbase + (size_t)(jt + 1) * TJ_ * QK_;
      kf0 = *(const float4*)(knext);
      kf1 = *(const float4*)(knext + 4);
    }
    // s via hi/lo MFMA (identical recipe to k_pbm -> values match pass B)
#pragma unroll
    for (int ih = 0; ih < 2; ih++) {
      f32x4 z = (f32x4)(0.f);
      z = __builtin_amdgcn_mfma_f32_16x16x32_bf16(ahf[ih], kh.f, z, 0, 0, 0);
      z = __builtin_amdgcn_mfma_f32_16x16x32_bf16(alf[ih], kh.f, z, 0, 0, 0);
      z = __builtin_amdgcn_mfma_f32_16x16x32_bf16(ahf[ih], klo.f, z, 0, 0, 0);
#pragma unroll
      for (int r = 0; r < 4; r++) {
        int k = ih * 4 + r;
        float sv = z[r];
        float nm = fmaxf(m8[k], sv);
        l8[k] = l8[k] * __expf(m8[k] - nm) + __expf(sv - nm);
        m8[k] = nm;
      }
    }
  }
  // merge across the 16 n16-lanes (butterfly over lane bits 0..3)
#pragma unroll
  for (int d = 1; d < 16; d <<= 1) {
#pragma unroll
    for (int k = 0; k < 8; k++) {
      float om = __shfl_xor(m8[k], d, 64);
      float ol = __shfl_xor(l8[k], d, 64);
      float nm = fmaxf(m8[k], om);
      l8[k] = l8[k] * __expf(m8[k] - nm) + ol * __expf(om - nm);
      m8[k] = nm;
    }
  }
  // n16==0 lanes hold per-wave (m,l) for rows ih*16+quad*4+r
  if (n16 == 0) {
#pragma unroll
    for (int ih = 0; ih < 2; ih++)
#pragma unroll
      for (int r = 0; r < 4; r++) {
        int i = ih * 16 + quad * 4 + r;
        red_m[wave * 32 + i] = m8[ih * 4 + r];
        red_l[wave * 32 + i] = l8[ih * 4 + r];
      }
  }
  __syncthreads();
  if (tid < 32) {
    float wm[4];
    float M = -3.0e38f;
#pragma unroll
    for (int w = 0; w < 4; w++) { wm[w] = red_m[w * 32 + tid]; M = fmaxf(M, wm[w]); }
    float L = 0.f;
#pragma unroll
    for (int w = 0; w < 4; w++) L += red_l[w * 32 + tid] * __expf(wm[w] - M);
    mrow[b * N_ + i0 + tid] = M;
    lrowi[b * N_ + i0 + tid] = 1.0f / L;
  }
}

// ---- k_pbm v3: pamT[b,i,c] = sum_j P(i,j) V[j,c], all-MFMA, 1 barrier/iter ----
// (R13 race-free structure; q-fragment loads hoisted out of the loop)
__global__ __launch_bounds__(256) void k_pbm(
    const float* __restrict__ qT, const float* __restrict__ kT, const bf16* __restrict__ vbf,
    const float* __restrict__ mrow, const float* __restrict__ lrowi,
    float* __restrict__ pamT) {
  int b = blockIdx.z;
  int cb0 = blockIdx.y * CH_;
  int i0 = blockIdx.x * TI_;
  int tid = threadIdx.x;
  int lane = tid & 63, wave = tid >> 6;
  int n16 = lane & 15, quad = lane >> 4;

  __shared__ __align__(16) bf16 q_hi[32 * KP_], q_lo[32 * KP_];
  __shared__ __align__(16) bf16 k_hi[64 * KP_], k_lo[64 * KP_];
  __shared__ __align__(16) bf16 v_s[128 * VP_];
  __shared__ __align__(16) bf16 p_s[2][32 * PP_];   // double-buffered (cross-wave)

  float mreg[8], lireg[8];
#pragma unroll
  for (int ih = 0; ih < 2; ih++)
#pragma unroll
    for (int r = 0; r < 4; r++) {
      int i = ih * 16 + quad * 4 + r;
      mreg[ih * 4 + r] = mrow[b * N_ + i0 + i];
      lireg[ih * 4 + r] = lrowi[b * N_ + i0 + i];
    }

  if (tid < 128) {
    int ir = tid >> 2, kq = (tid & 3) * 8;
    const float4* qs4 = (const float4*)(qT + ((size_t)b * N_ + i0 + ir) * QK_ + kq);
    float4 f0 = qs4[0], f1 = qs4[1];
    float f[8] = {f0.x, f0.y, f0.z, f0.w, f1.x, f1.y, f1.z, f1.w};
    bf8pack uh, ul;
#pragma unroll
    for (int u = 0; u < 8; u++) {
      bf16 h = __float2bfloat16(f[u]);
      uh.h[u] = h;
      ul.h[u] = __float2bfloat16(f[u] - __bfloat162float(h));
    }
    *(int4*)(q_hi + ir * KP_ + kq) = uh.v;
    *(int4*)(q_lo + ir * KP_ + kq) = ul.v;
  }

  f32x4 acc[2][2];
#pragma unroll
  for (int ih = 0; ih < 2; ih++)
#pragma unroll
    for (int cb = 0; cb < 2; cb++) acc[ih][cb] = (f32x4)(0.f);

  int jr = tid >> 2, kq = (tid & 3) * 8;
  int vc = tid >> 1, vjh = (tid & 1) * 32;

  float4 kf0, kf1;
  int4 vf0, vf1, vf2, vf3;
  {
    const float4* ks4 = (const float4*)(kT + ((size_t)b * N_ + jr) * QK_ + kq);
    kf0 = ks4[0]; kf1 = ks4[1];
    const int4* vs4 = (const int4*)(vbf + ((size_t)b * C_ + cb0 + vc) * N_ + vjh);
    vf0 = vs4[0]; vf1 = vs4[1]; vf2 = vs4[2]; vf3 = vs4[3];
  }

  __syncthreads();   // Q visible to all waves

  // hoist loop-invariant Q fragments
  bf16x8f ahf[2], alf[2];
#pragma unroll
  for (int ih = 0; ih < 2; ih++) {
    ahf[ih] = *(const bf16x8f*)(const void*)(q_hi + (ih * 16 + n16) * KP_ + quad * 8);
    alf[ih] = *(const bf16x8f*)(const void*)(q_lo + (ih * 16 + n16) * KP_ + quad * 8);
  }

  for (int jt = 0; jt < N_ / TJ_; jt++) {
    {
      float f[8] = {kf0.x, kf0.y, kf0.z, kf0.w, kf1.x, kf1.y, kf1.z, kf1.w};
      bf8pack uh, ul;
#pragma unroll
      for (int u = 0; u < 8; u++) {
        bf16 h = __float2bfloat16(f[u]);
        uh.h[u] = h;
        ul.h[u] = __float2bfloat16(f[u] - __bfloat162float(h));
      }
      *(int4*)(k_hi + jr * KP_ + kq) = uh.v;
      *(int4*)(k_lo + jr * KP_ + kq) = ul.v;
      int4* vd = (int4*)(v_s + vc * VP_ + vjh);
      vd[0] = vf0; vd[1] = vf1; vd[2] = vf2; vd[3] = vf3;
    }
    if (jt + 1 < N_ / TJ_) {
      int j0n = (jt + 1) * TJ_;
      const float4* ks4 = (const float4*)(kT + ((size_t)b * N_ + j0n + jr) * QK_ + kq);
      kf0 = ks4[0]; kf1 = ks4[1];
      const int4* vs4 = (const int4*)(vbf + ((size_t)b * C_ + cb0 + vc) * N_ + j0n + vjh);
      vf0 = vs4[0]; vf1 = vs4[1]; vf2 = vs4[2]; vf3 = vs4[3];
    }
    f32x4 s[2];
    {
      bf16x8f bh = *(const bf16x8f*)(const void*)(k_hi + (wave * 16 + n16) * KP_ + quad * 8);
      bf16x8f bl = *(const bf16x8f*)(const void*)(k_lo + (wave * 16 + n16) * KP_ + quad * 8);
#pragma unroll
      for (int ih = 0; ih < 2; ih++) {
        f32x4 z = (f32x4)(0.f);
        z = __builtin_amdgcn_mfma_f32_16x16x32_bf16(ahf[ih], bh, z, 0, 0, 0);
        z = __builtin_amdgcn_mfma_f32_16x16x32_bf16(alf[ih], bh, z, 0, 0, 0);
        z = __builtin_amdgcn_mfma_f32_16x16x32_bf16(ahf[ih], bl, z, 0, 0, 0);
        s[ih] = z;
      }
    }
    bf16* pbuf = p_s[jt & 1];
#pragma unroll
    for (int ih = 0; ih < 2; ih++)
#pragma unroll
      for (int r = 0; r < 4; r++) {
        int i = ih * 16 + quad * 4 + r;
        float p = __expf(s[ih][r] - mreg[ih * 4 + r]) * lireg[ih * 4 + r];
        pbuf[i * PP_ + wave * 16 + n16] = __float2bfloat16(p);
      }
    __syncthreads();   // the ONE barrier per iter
    bf16x8f pa0[2], pa1[2], vb0[2], vb1[2];
#pragma unroll
    for (int ih = 0; ih < 2; ih++) {
      pa0[ih] = *(const bf16x8f*)(const void*)(pbuf + (ih * 16 + n16) * PP_ + quad * 8);
      pa1[ih] = *(const bf16x8f*)(const void*)(pbuf + (ih * 16 + n16) * PP_ + 32 + quad * 8);
    }
#pragma unroll
    for (int cb = 0; cb < 2; cb++) {
      vb0[cb] = *(const bf16x8f*)(const void*)(v_s + (wave * 32 + cb * 16 + n16) * VP_ + quad * 8);
      vb1[cb] = *(const bf16x8f*)(const void*)(v_s + (wave * 32 + cb * 16 + n16) * VP_ + 32 + quad * 8);
    }
#pragma unroll
    for (int ih = 0; ih < 2; ih++)
#pragma unroll
      for (int cb = 0; cb < 2; cb++) {
        acc[ih][cb] = __builtin_amdgcn_mfma_f32_16x16x32_bf16(pa0[ih], vb0[cb], acc[ih][cb], 0, 0, 0);
        acc[ih][cb] = __builtin_amdgcn_mfma_f32_16x16x32_bf16(pa1[ih], vb1[cb], acc[ih][cb], 0, 0, 0);
      }
  }
#pragma unroll
  for (int ih = 0; ih < 2; ih++)
#pragma unroll
    for (int cb = 0; cb < 2; cb++) {
      int c = cb0 + wave * 32 + cb * 16 + n16;
#pragma unroll
      for (int r = 0; r < 4; r++) {
        int i = ih * 16 + quad * 4 + r;
        pamT[((size_t)b * N_ + i0 + i) * C_ + c] = acc[ih][cb][r];
      }
    }
}

// ---- k_ce: CAM energy partials over K-chunks ----
__global__ __launch_bounds__(256) void k_ce(const float* __restrict__ x, float* __restrict__ eCp) {
  int b = blockIdx.z;
  int kc = blockIdx.y;
  int it = blockIdx.x & 7, jt = blockIdx.x >> 3;
  int i0 = it * 32, j0 = jt * 32;
  __shared__ float xi[32 * 65], xj[32 * 65];
  int tid = threadIdx.x;
  int ti2 = (tid & 15) * 2, tj2 = (tid >> 4) * 2;
  float a00 = 0.f, a01 = 0.f, a10 = 0.f, a11 = 0.f;
  for (int n0 = 0; n0 < 512; n0 += 64) {
    __syncthreads();
#pragma unroll
    for (int k = 0; k < 8; k++) {
      int e = k * 256 + tid;
      int r = e >> 6, c = e & 63;
      xi[r * 65 + c] = x[((size_t)b * C_ + i0 + r) * N_ + kc * 512 + n0 + c];
      xj[r * 65 + c] = x[((size_t)b * C_ + j0 + r) * N_ + kc * 512 + n0 + c];
    }
    __syncthreads();
#pragma unroll 4
    for (int n = 0; n < 64; n++) {
      float u0 = xi[ti2 * 65 + n], u1 = xi[(ti2 + 1) * 65 + n];
      float w0 = xj[tj2 * 65 + n], w1 = xj[(tj2 + 1) * 65 + n];
      a00 += u0 * w0; a01 += u0 * w1; a10 += u1 * w0; a11 += u1 * w1;
    }
  }
  float* dst = eCp + (((size_t)kc * B_ + b) * C_ + i0) * C_ + j0;
  dst[(ti2 + 0) * C_ + tj2 + 0] = a00;
  dst[(ti2 + 0) * C_ + tj2 + 1] = a01;
  dst[(ti2 + 1) * C_ + tj2 + 0] = a10;
  dst[(ti2 + 1) * C_ + tj2 + 1] = a11;
}

// ---- k_cs: CAM softmax over -e ----
__global__ __launch_bounds__(256) void k_cs(const float* __restrict__ eCp, float* __restrict__ attnC) {
  int row = blockIdx.x;
  int b = row >> 8, i = row & 255;
  int j = threadIdx.x;
  float e = 0.f;
#pragma unroll
  for (int kc = 0; kc < 8; kc++) e += eCp[(((size_t)kc * B_ + b) * C_ + i) * C_ + j];
  float ne = -e;
  __shared__ float buf[256];
  buf[j] = ne;
  __syncthreads();
  for (int st = 128; st >= 1; st >>= 1) {
    if (j < st) buf[j] = fmaxf(buf[j], buf[j + st]);
    __syncthreads();
  }
  float m = buf[0];
  __syncthreads();
  float p = __expf(ne - m);
  buf[j] = p;
  __syncthreads();
  for (int st = 128; st >= 1; st >>= 1) {
    if (j < st) buf[j] += buf[j + st];
    __syncthreads();
  }
  attnC[(size_t)row * C_ + j] = p / buf[0];
}

// ---- k_co: CAM out + combine -> fp32 out ----
__global__ __launch_bounds__(256) void k_co(
    const float* __restrict__ x, const float* __restrict__ attnC, const float* __restrict__ pamT,
    const float* __restrict__ gpam, const float* __restrict__ gcam, float* __restrict__ out) {
  int b = blockIdx.z, c0 = blockIdx.y * 32, n0 = blockIdx.x * 256;
  int tid = threadIdx.x;
  __shared__ float pam_s[256 * 33];
#pragma unroll
  for (int k = 0; k < 32; k++) {
    int e = k * 256 + tid;
    int r = e >> 5, cc = e & 31;
    pam_s[r * 33 + cc] = pamT[((size_t)b * N_ + n0 + r) * C_ + c0 + cc];
  }
  __syncthreads();
  float acc[32];
#pragma unroll
  for (int i = 0; i < 32; i++) acc[i] = 0.f;
  const float* arow = attnC + ((size_t)b * C_ + c0) * C_;
  for (int j = 0; j < C_; j++) {
    float xv = x[((size_t)b * C_ + j) * N_ + n0 + tid];
#pragma unroll
    for (int i = 0; i < 32; i++) acc[i] += arow[i * C_ + j] * xv;
  }
  float gp = gpam[0], gc = gcam[0];
#pragma unroll
  for (int i = 0; i < 32; i++) {
    size_t idx = ((size_t)b * C_ + c0 + i) * N_ + n0 + tid;
    out[idx] = gp * pam_s[tid * 33 + i] + gc * acc[i] + 2.0f * x[idx];
  }
}

extern "C" void kernel_launch(void* const* d_in, const int* in_sizes, int n_in,
                              void* d_out, int out_size, void* d_ws, size_t ws_size,
                              hipStream_t stream) {
  const float* x  = (const float*)d_in[0];
  const float* wq = (const float*)d_in[1];
  const float* bq = (const float*)d_in[2];
  const float* wk = (const float*)d_in[3];
  const float* bk = (const float*)d_in[4];
  const float* wv = (const float*)d_in[5];
  const float* bv = (const float*)d_in[6];
  const float* gp = (const float*)d_in[7];
  const float* gc = (const float*)d_in[8];
  float* out = (float*)d_out;

  float* ws = (float*)d_ws;
  size_t o = 0;
  float* qT    = ws + o; o += (size_t)B_ * N_ * QK_;    // 262144
  float* kT    = ws + o; o += (size_t)B_ * N_ * QK_;    // 262144
  float* pamT  = ws + o; o += (size_t)B_ * N_ * C_;     // 2097152
  float* mrow  = ws + o; o += (size_t)B_ * N_;          // 8192
  float* lrowi = ws + o; o += (size_t)B_ * N_;          // 8192
  float* eCp   = ws + o; o += (size_t)8 * B_ * C_ * C_; // 1048576
  float* attnC = ws + o; o += (size_t)B_ * C_ * C_;     // 131072
  bf16*  vbf   = (bf16*)(ws + o); o += (size_t)B_ * N_ * C_ / 2;  // 1048576
  float* qpprt = ws + o; o += (size_t)4 * B_ * N_ * QK_; // 1048576
  float* kpprt = ws + o; o += (size_t)4 * B_ * N_ * QK_; // 1048576
  // total ~7.0 M floats = 28 MB

  k_qk1<<<dim3(16, 4, B_), dim3(256), 0, stream>>>(x, wq, wk, qpprt, kpprt);
  k_qk2<<<dim3(32), dim3(256), 0, stream>>>(qpprt, kpprt, bq, bk, qT, kT);
  k_vbf<<<dim3(16, 32, B_), dim3(256), 0, stream>>>(x, wv, bv, vbf);
  k_pam2<<<dim3(N_ / TI_, B_), dim3(256), 0, stream>>>(qT, kT, mrow, lrowi);
  k_pbm<<<dim3(N_ / TI_, C_ / CH_, B_), dim3(256), 0, stream>>>(qT, kT, vbf, mrow, lrowi, pamT);
  k_ce<<<dim3(64, 8, B_), dim3(256), 0, stream>>>(x, eCp);
  k_cs<<<dim3(B_ * C_), dim3(256), 0, stream>>>(eCp, attnC);
  k_co<<<dim3(16, 8, B_), dim3(256), 0, stream>>>(x, attnC, pamT, gp, gc, out);
}

// Round 17
// 356.018 us; speedup vs baseline: 8.6739x; 1.0006x over previous
//
#include <hip/hip_runtime.h>
#include <hip/hip_bf16.h>

// DA block (DANet) — Round 17: k_pbm v4 — LDS-free staging.
//  R16 counters: k_pbm 78.7us, LDS-port math ≈51us + 12us conflicts -> LDS-bound.
//  v4: (1) K/V/Q MFMA fragments loaded DIRECT from global (wave-local anyway);
//      (2) hi/lo bf16 split precomputed once in k_qk2 (qhi/qlo/khi/klo arrays,
//          bit-identical recipe -> s unchanged); zero in-loop cvt;
//      (3) CH_ 128->256: s-tile computed once (grid 256 = 1 blk/CU, tiny LDS),
//          V/K register-prefetched 1 iter ahead.
//  LDS now = p_s double-buffer round-trip only (R13 race-free structure, 1 barrier/iter).
//  k_pam2 v2: same direct-global hi/lo frags (no LDS Q stage, no in-loop cvt).
// Inputs fp32 dict order; output fp32.

#define B_ 2
#define C_ 256
#define N_ 4096
#define QK_ 32

#define TI_ 32     // i-rows per block (pass A & B)
#define TJ_ 64     // j per tile
#define PP_ 72     // p LDS pitch (bf16) = 144 B (rows n16/n16+8 alias 2-way = free)

typedef __hip_bfloat16 bf16;
typedef __attribute__((ext_vector_type(8))) short bf16x8f;   // MFMA A/B frag
typedef __attribute__((ext_vector_type(4))) float f32x4;     // MFMA C/D frag

union bf8pack { bf16 h[8]; int4 v; bf16x8f f; };

// ---- k_qk1: partial Q,K projections over a 64-channel chunk ----
__global__ __launch_bounds__(256) void k_qk1(
    const float* __restrict__ x, const float* __restrict__ wq, const float* __restrict__ wk,
    float* __restrict__ qp, float* __restrict__ kp) {
  int b = blockIdx.z;
  int cg = blockIdx.y;                      // 4 chunks of 64 channels
  int n = blockIdx.x * 256 + threadIdx.x;
  float qa[QK_], ka[QK_];
#pragma unroll
  for (int o = 0; o < QK_; o++) { qa[o] = 0.f; ka[o] = 0.f; }
  const float* xp = x + ((size_t)b * C_ + cg * 64) * N_ + n;
  for (int c = 0; c < 64; c++) {
    float xv = xp[(size_t)c * N_];
    int cc = cg * 64 + c;
#pragma unroll
    for (int o = 0; o < QK_; o++) {
      qa[o] += wq[o * C_ + cc] * xv;   // uniform weight loads -> scalar path
      ka[o] += wk[o * C_ + cc] * xv;
    }
  }
  float4* qo = (float4*)(qp + (((size_t)cg * B_ + b) * N_ + n) * QK_);
  float4* ko = (float4*)(kp + (((size_t)cg * B_ + b) * N_ + n) * QK_);
#pragma unroll
  for (int u = 0; u < 8; u++) {
    qo[u] = make_float4(qa[4 * u], qa[4 * u + 1], qa[4 * u + 2], qa[4 * u + 3]);
    ko[u] = make_float4(ka[4 * u], ka[4 * u + 1], ka[4 * u + 2], ka[4 * u + 3]);
  }
}

// ---- k_qk2 v2: combine partials + bias, emit hi/lo bf16 split arrays ----
__global__ __launch_bounds__(256) void k_qk2(
    const float* __restrict__ qp, const float* __restrict__ kp,
    const float* __restrict__ bq, const float* __restrict__ bk,
    bf16* __restrict__ qhi, bf16* __restrict__ qlo,
    bf16* __restrict__ khi, bf16* __restrict__ klo) {
  int t = blockIdx.x * 256 + threadIdx.x;    // b*N + n
  int b = t >> 12, n = t & (N_ - 1);
  float qa[QK_], ka[QK_];
#pragma unroll
  for (int o = 0; o < QK_; o++) { qa[o] = bq[o]; ka[o] = bk[o]; }
#pragma unroll
  for (int cg = 0; cg < 4; cg++) {
    const float4* qs = (const float4*)(qp + (((size_t)cg * B_ + b) * N_ + n) * QK_);
    const float4* ks = (const float4*)(kp + (((size_t)cg * B_ + b) * N_ + n) * QK_);
#pragma unroll
    for (int u = 0; u < 8; u++) {
      float4 q4 = qs[u], k4 = ks[u];
      qa[4 * u] += q4.x; qa[4 * u + 1] += q4.y; qa[4 * u + 2] += q4.z; qa[4 * u + 3] += q4.w;
      ka[4 * u] += k4.x; ka[4 * u + 1] += k4.y; ka[4 * u + 2] += k4.z; ka[4 * u + 3] += k4.w;
    }
  }
  size_t base = (size_t)t * QK_;
#pragma unroll
  for (int g = 0; g < 4; g++) {
    bf8pack qh, ql, kh, kl;
#pragma unroll
    for (int u = 0; u < 8; u++) {
      float qv = qa[g * 8 + u], kv = ka[g * 8 + u];
      bf16 qhh = __float2bfloat16(qv);
      bf16 khh = __float2bfloat16(kv);
      qh.h[u] = qhh; ql.h[u] = __float2bfloat16(qv - __bfloat162float(qhh));
      kh.h[u] = khh; kl.h[u] = __float2bfloat16(kv - __bfloat162float(khh));
    }
    *(int4*)(qhi + base + g * 8) = qh.v;
    *(int4*)(qlo + base + g * 8) = ql.v;
    *(int4*)(khi + base + g * 8) = kh.v;
    *(int4*)(klo + base + g * 8) = kl.v;
  }
}

// ---- k_vbf: V proj -> vbf[b,c,j] bf16; 8 channels/block ----
__global__ __launch_bounds__(256) void k_vbf(
    const float* __restrict__ x, const float* __restrict__ wv, const float* __restrict__ bv,
    bf16* __restrict__ vbf) {
  int b = blockIdx.z;
  int co0 = blockIdx.y * 8;
  int n0 = blockIdx.x * 256;
  int tid = threadIdx.x;
  float acc[8];
#pragma unroll
  for (int o = 0; o < 8; o++) acc[o] = bv[co0 + o];
  const float* xp = x + (size_t)b * C_ * N_ + n0 + tid;
  for (int c = 0; c < C_; c++) {
    float xv = xp[(size_t)c * N_];
#pragma unroll
    for (int o = 0; o < 8; o++) acc[o] += wv[(co0 + o) * C_ + c] * xv;
  }
#pragma unroll
  for (int o = 0; o < 8; o++)
    vbf[((size_t)b * C_ + co0 + o) * N_ + n0 + tid] = __float2bfloat16(acc[o]);
}

// ---- k_pam2 v2: MFMA pass A — direct-global hi/lo frags, no LDS in loop ----
__global__ __launch_bounds__(256) void k_pam2(
    const bf16* __restrict__ qhi, const bf16* __restrict__ qlo,
    const bf16* __restrict__ khi, const bf16* __restrict__ klo,
    float* __restrict__ mrow, float* __restrict__ lrowi) {
  int b = blockIdx.y;
  int i0 = blockIdx.x * TI_;
  int tid = threadIdx.x;
  int lane = tid & 63, wave = tid >> 6;
  int n16 = lane & 15, quad = lane >> 4;

  __shared__ float red_m[4 * 32], red_l[4 * 32];

  // Q frags direct from global (loop-invariant)
  bf16x8f ahf[2], alf[2];
#pragma unroll
  for (int ih = 0; ih < 2; ih++) {
    size_t qoff = ((size_t)b * N_ + i0 + ih * 16 + n16) * QK_ + quad * 8;
    ahf[ih] = *(const bf16x8f*)(const void*)(qhi + qoff);
    alf[ih] = *(const bf16x8f*)(const void*)(qlo + qoff);
  }

  float m8[8], l8[8];
#pragma unroll
  for (int k = 0; k < 8; k++) { m8[k] = -3.0e38f; l8[k] = 0.f; }

  const bf16* khb = khi + ((size_t)b * N_ + wave * 16 + n16) * QK_ + quad * 8;
  const bf16* klb = klo + ((size_t)b * N_ + wave * 16 + n16) * QK_ + quad * 8;
  bf16x8f khf = *(const bf16x8f*)(const void*)khb;
  bf16x8f klf = *(const bf16x8f*)(const void*)klb;

  for (int jt = 0; jt < N_ / TJ_; jt++) {
    bf16x8f khn, kln;
    if (jt + 1 < N_ / TJ_) {
      size_t off = (size_t)(jt + 1) * TJ_ * QK_;
      khn = *(const bf16x8f*)(const void*)(khb + off);
      kln = *(const bf16x8f*)(const void*)(klb + off);
    }
#pragma unroll
    for (int ih = 0; ih < 2; ih++) {
      f32x4 z = (f32x4)(0.f);
      z = __builtin_amdgcn_mfma_f32_16x16x32_bf16(ahf[ih], khf, z, 0, 0, 0);
      z = __builtin_amdgcn_mfma_f32_16x16x32_bf16(alf[ih], khf, z, 0, 0, 0);
      z = __builtin_amdgcn_mfma_f32_16x16x32_bf16(ahf[ih], klf, z, 0, 0, 0);
#pragma unroll
      for (int r = 0; r < 4; r++) {
        int k = ih * 4 + r;
        float sv = z[r];
        float nm = fmaxf(m8[k], sv);
        l8[k] = l8[k] * __expf(m8[k] - nm) + __expf(sv - nm);
        m8[k] = nm;
      }
    }
    khf = khn; klf = kln;
  }
  // merge across the 16 n16-lanes (butterfly over lane bits 0..3)
#pragma unroll
  for (int d = 1; d < 16; d <<= 1) {
#pragma unroll
    for (int k = 0; k < 8; k++) {
      float om = __shfl_xor(m8[k], d, 64);
      float ol = __shfl_xor(l8[k], d, 64);
      float nm = fmaxf(m8[k], om);
      l8[k] = l8[k] * __expf(m8[k] - nm) + ol * __expf(om - nm);
      m8[k] = nm;
    }
  }
  if (n16 == 0) {
#pragma unroll
    for (int ih = 0; ih < 2; ih++)
#pragma unroll
      for (int r = 0; r < 4; r++) {
        int i = ih * 16 + quad * 4 + r;
        red_m[wave * 32 + i] = m8[ih * 4 + r];
        red_l[wave * 32 + i] = l8[ih * 4 + r];
      }
  }
  __syncthreads();
  if (tid < 32) {
    float wm[4];
    float M = -3.0e38f;
#pragma unroll
    for (int w = 0; w < 4; w++) { wm[w] = red_m[w * 32 + tid]; M = fmaxf(M, wm[w]); }
    float L = 0.f;
#pragma unroll
    for (int w = 0; w < 4; w++) L += red_l[w * 32 + tid] * __expf(wm[w] - M);
    mrow[b * N_ + i0 + tid] = M;
    lrowi[b * N_ + i0 + tid] = 1.0f / L;
  }
}

// ---- k_pbm v4: pamT[b,i,c] = sum_j P(i,j) V[j,c]; LDS = p_s only ----
// 256 thr = 4 waves; 32 i-rows; ALL 256 channels (wave w owns c = w*64+cb*16+n16).
// s-tile computed once per block. K/V frags direct global, 1-iter prefetch.
__global__ __launch_bounds__(256) void k_pbm(
    const bf16* __restrict__ qhi, const bf16* __restrict__ qlo,
    const bf16* __restrict__ khi, const bf16* __restrict__ klo,
    const bf16* __restrict__ vbf,
    const float* __restrict__ mrow, const float* __restrict__ lrowi,
    float* __restrict__ pamT) {
  int b = blockIdx.y;
  int i0 = blockIdx.x * TI_;
  int tid = threadIdx.x;
  int lane = tid & 63, wave = tid >> 6;
  int n16 = lane & 15, quad = lane >> 4;

  __shared__ __align__(16) bf16 p_s[2][32 * PP_];   // double-buffered (cross-wave)

  float mreg[8], lireg[8];
#pragma unroll
  for (int ih = 0; ih < 2; ih++)
#pragma unroll
    for (int r = 0; r < 4; r++) {
      int i = ih * 16 + quad * 4 + r;
      mreg[ih * 4 + r] = mrow[b * N_ + i0 + i];
      lireg[ih * 4 + r] = lrowi[b * N_ + i0 + i];
    }

  // Q frags direct from global (loop-invariant)
  bf16x8f ahf[2], alf[2];
#pragma unroll
  for (int ih = 0; ih < 2; ih++) {
    size_t qoff = ((size_t)b * N_ + i0 + ih * 16 + n16) * QK_ + quad * 8;
    ahf[ih] = *(const bf16x8f*)(const void*)(qhi + qoff);
    alf[ih] = *(const bf16x8f*)(const void*)(qlo + qoff);
  }

  f32x4 acc[2][4];
#pragma unroll
  for (int ih = 0; ih < 2; ih++)
#pragma unroll
    for (int cb = 0; cb < 4; cb++) acc[ih][cb] = (f32x4)(0.f);

  // K frag base (row wave*16+n16), V bases (channel wave*64+cb*16+n16)
  const bf16* khb = khi + ((size_t)b * N_ + wave * 16 + n16) * QK_ + quad * 8;
  const bf16* klb = klo + ((size_t)b * N_ + wave * 16 + n16) * QK_ + quad * 8;
  const bf16* vb0 = vbf + ((size_t)b * C_ + wave * 64 + n16) * N_ + quad * 8;

  bf16x8f khf = *(const bf16x8f*)(const void*)khb;
  bf16x8f klf = *(const bf16x8f*)(const void*)klb;
  bf16x8f vcur[4][2];
#pragma unroll
  for (int cb = 0; cb < 4; cb++)
#pragma unroll
    for (int h = 0; h < 2; h++)
      vcur[cb][h] = *(const bf16x8f*)(const void*)(vb0 + (size_t)cb * 16 * N_ + h * 32);

  for (int jt = 0; jt < N_ / TJ_; jt++) {
    // prefetch next tile's K and V frags (consumed next iter)
    bf16x8f khn, kln, vnxt[4][2];
    if (jt + 1 < N_ / TJ_) {
      size_t koff = (size_t)(jt + 1) * TJ_ * QK_;
      khn = *(const bf16x8f*)(const void*)(khb + koff);
      kln = *(const bf16x8f*)(const void*)(klb + koff);
      int jb = (jt + 1) * TJ_;
#pragma unroll
      for (int cb = 0; cb < 4; cb++)
#pragma unroll
        for (int h = 0; h < 2; h++)
          vnxt[cb][h] = *(const bf16x8f*)(const void*)(vb0 + (size_t)cb * 16 * N_ + jb + h * 32);
    }
    // s-tile via hi/lo MFMA (identical recipe to k_pam2 -> consistent softmax)
    f32x4 s[2];
#pragma unroll
    for (int ih = 0; ih < 2; ih++) {
      f32x4 z = (f32x4)(0.f);
      z = __builtin_amdgcn_mfma_f32_16x16x32_bf16(ahf[ih], khf, z, 0, 0, 0);
      z = __builtin_amdgcn_mfma_f32_16x16x32_bf16(alf[ih], khf, z, 0, 0, 0);
      z = __builtin_amdgcn_mfma_f32_16x16x32_bf16(ahf[ih], klf, z, 0, 0, 0);
      s[ih] = z;
    }
    // P = exp(s - m) * (1/l) -> p_s[jt&1]  (col j = wave*16+n16, row i = quad*4+r)
    bf16* pbuf = p_s[jt & 1];
#pragma unroll
    for (int ih = 0; ih < 2; ih++)
#pragma unroll
      for (int r = 0; r < 4; r++) {
        int i = ih * 16 + quad * 4 + r;
        float p = __expf(s[ih][r] - mreg[ih * 4 + r]) * lireg[ih * 4 + r];
        pbuf[i * PP_ + wave * 16 + n16] = __float2bfloat16(p);
      }
    __syncthreads();   // the ONE barrier: P(jt) visible; buffer jt+1 is the other one
    // A frags from p_s; B frags = this iter's V (prefetched)
    bf16x8f pa0[2], pa1[2];
#pragma unroll
    for (int ih = 0; ih < 2; ih++) {
      pa0[ih] = *(const bf16x8f*)(const void*)(pbuf + (ih * 16 + n16) * PP_ + quad * 8);
      pa1[ih] = *(const bf16x8f*)(const void*)(pbuf + (ih * 16 + n16) * PP_ + 32 + quad * 8);
    }
#pragma unroll
    for (int ih = 0; ih < 2; ih++)
#pragma unroll
      for (int cb = 0; cb < 4; cb++) {
        acc[ih][cb] = __builtin_amdgcn_mfma_f32_16x16x32_bf16(pa0[ih], vcur[cb][0], acc[ih][cb], 0, 0, 0);
        acc[ih][cb] = __builtin_amdgcn_mfma_f32_16x16x32_bf16(pa1[ih], vcur[cb][1], acc[ih][cb], 0, 0, 0);
      }
    khf = khn; klf = kln;
#pragma unroll
    for (int cb = 0; cb < 4; cb++)
#pragma unroll
      for (int h = 0; h < 2; h++) vcur[cb][h] = vnxt[cb][h];
  }
  // epilogue: C/D layout col=lane&15, row=quad*4+r; c = wave*64+cb*16+n16
#pragma unroll
  for (int ih = 0; ih < 2; ih++)
#pragma unroll
    for (int cb = 0; cb < 4; cb++) {
      int c = wave * 64 + cb * 16 + n16;
#pragma unroll
      for (int r = 0; r < 4; r++) {
        int i = ih * 16 + quad * 4 + r;
        pamT[((size_t)b * N_ + i0 + i) * C_ + c] = acc[ih][cb][r];
      }
    }
}

// ---- k_ce: CAM energy partials over K-chunks ----
__global__ __launch_bounds__(256) void k_ce(const float* __restrict__ x, float* __restrict__ eCp) {
  int b = blockIdx.z;
  int kc = blockIdx.y;
  int it = blockIdx.x & 7, jt = blockIdx.x >> 3;
  int i0 = it * 32, j0 = jt * 32;
  __shared__ float xi[32 * 65], xj[32 * 65];
  int tid = threadIdx.x;
  int ti2 = (tid & 15) * 2, tj2 = (tid >> 4) * 2;
  float a00 = 0.f, a01 = 0.f, a10 = 0.f, a11 = 0.f;
  for (int n0 = 0; n0 < 512; n0 += 64) {
    __syncthreads();
#pragma unroll
    for (int k = 0; k < 8; k++) {
      int e = k * 256 + tid;
      int r = e >> 6, c = e & 63;
      xi[r * 65 + c] = x[((size_t)b * C_ + i0 + r) * N_ + kc * 512 + n0 + c];
      xj[r * 65 + c] = x[((size_t)b * C_ + j0 + r) * N_ + kc * 512 + n0 + c];
    }
    __syncthreads();
#pragma unroll 4
    for (int n = 0; n < 64; n++) {
      float u0 = xi[ti2 * 65 + n], u1 = xi[(ti2 + 1) * 65 + n];
      float w0 = xj[tj2 * 65 + n], w1 = xj[(tj2 + 1) * 65 + n];
      a00 += u0 * w0; a01 += u0 * w1; a10 += u1 * w0; a11 += u1 * w1;
    }
  }
  float* dst = eCp + (((size_t)kc * B_ + b) * C_ + i0) * C_ + j0;
  dst[(ti2 + 0) * C_ + tj2 + 0] = a00;
  dst[(ti2 + 0) * C_ + tj2 + 1] = a01;
  dst[(ti2 + 1) * C_ + tj2 + 0] = a10;
  dst[(ti2 + 1) * C_ + tj2 + 1] = a11;
}

// ---- k_cs: CAM softmax over -e ----
__global__ __launch_bounds__(256) void k_cs(const float* __restrict__ eCp, float* __restrict__ attnC) {
  int row = blockIdx.x;
  int b = row >> 8, i = row & 255;
  int j = threadIdx.x;
  float e = 0.f;
#pragma unroll
  for (int kc = 0; kc < 8; kc++) e += eCp[(((size_t)kc * B_ + b) * C_ + i) * C_ + j];
  float ne = -e;
  __shared__ float buf[256];
  buf[j] = ne;
  __syncthreads();
  for (int st = 128; st >= 1; st >>= 1) {
    if (j < st) buf[j] = fmaxf(buf[j], buf[j + st]);
    __syncthreads();
  }
  float m = buf[0];
  __syncthreads();
  float p = __expf(ne - m);
  buf[j] = p;
  __syncthreads();
  for (int st = 128; st >= 1; st >>= 1) {
    if (j < st) buf[j] += buf[j + st];
    __syncthreads();
  }
  attnC[(size_t)row * C_ + j] = p / buf[0];
}

// ---- k_co: CAM out + combine -> fp32 out ----
__global__ __launch_bounds__(256) void k_co(
    const float* __restrict__ x, const float* __restrict__ attnC, const float* __restrict__ pamT,
    const float* __restrict__ gpam, const float* __restrict__ gcam, float* __restrict__ out) {
  int b = blockIdx.z, c0 = blockIdx.y * 32, n0 = blockIdx.x * 256;
  int tid = threadIdx.x;
  __shared__ float pam_s[256 * 33];
#pragma unroll
  for (int k = 0; k < 32; k++) {
    int e = k * 256 + tid;
    int r = e >> 5, cc = e & 31;
    pam_s[r * 33 + cc] = pamT[((size_t)b * N_ + n0 + r) * C_ + c0 + cc];
  }
  __syncthreads();
  float acc[32];
#pragma unroll
  for (int i = 0; i < 32; i++) acc[i] = 0.f;
  const float* arow = attnC + ((size_t)b * C_ + c0) * C_;
  for (int j = 0; j < C_; j++) {
    float xv = x[((size_t)b * C_ + j) * N_ + n0 + tid];
#pragma unroll
    for (int i = 0; i < 32; i++) acc[i] += arow[i * C_ + j] * xv;
  }
  float gp = gpam[0], gc = gcam[0];
#pragma unroll
  for (int i = 0; i < 32; i++) {
    size_t idx = ((size_t)b * C_ + c0 + i) * N_ + n0 + tid;
    out[idx] = gp * pam_s[tid * 33 + i] + gc * acc[i] + 2.0f * x[idx];
  }
}

extern "C" void kernel_launch(void* const* d_in, const int* in_sizes, int n_in,
                              void* d_out, int out_size, void* d_ws, size_t ws_size,
                              hipStream_t stream) {
  const float* x  = (const float*)d_in[0];
  const float* wq = (const float*)d_in[1];
  const float* bq = (const float*)d_in[2];
  const float* wk = (const float*)d_in[3];
  const float* bk = (const float*)d_in[4];
  const float* wv = (const float*)d_in[5];
  const float* bv = (const float*)d_in[6];
  const float* gp = (const float*)d_in[7];
  const float* gc = (const float*)d_in[8];
  float* out = (float*)d_out;

  float* ws = (float*)d_ws;
  size_t o = 0;
  float* pamT  = ws + o; o += (size_t)B_ * N_ * C_;     // 2097152
  float* mrow  = ws + o; o += (size_t)B_ * N_;          // 8192
  float* lrowi = ws + o; o += (size_t)B_ * N_;          // 8192
  float* eCp   = ws + o; o += (size_t)8 * B_ * C_ * C_; // 1048576
  float* attnC = ws + o; o += (size_t)B_ * C_ * C_;     // 131072
  bf16*  vbf   = (bf16*)(ws + o); o += (size_t)B_ * N_ * C_ / 2;   // 1048576
  bf16*  qhi   = (bf16*)(ws + o); o += (size_t)B_ * N_ * QK_ / 2;  // 131072
  bf16*  qlo   = (bf16*)(ws + o); o += (size_t)B_ * N_ * QK_ / 2;  // 131072
  bf16*  khi   = (bf16*)(ws + o); o += (size_t)B_ * N_ * QK_ / 2;  // 131072
  bf16*  klo   = (bf16*)(ws + o); o += (size_t)B_ * N_ * QK_ / 2;  // 131072
  float* qpprt = ws + o; o += (size_t)4 * B_ * N_ * QK_; // 1048576
  float* kpprt = ws + o; o += (size_t)4 * B_ * N_ * QK_; // 1048576
  // total ~6.8 M floats = 27.3 MB

  k_qk1<<<dim3(16, 4, B_), dim3(256), 0, stream>>>(x, wq, wk, qpprt, kpprt);
  k_qk2<<<dim3(32), dim3(256), 0, stream>>>(qpprt, kpprt, bq, bk, qhi, qlo, khi, klo);
  k_vbf<<<dim3(16, 32, B_), dim3(256), 0, stream>>>(x, wv, bv, vbf);
  k_pam2<<<dim3(N_ / TI_, B_), dim3(256), 0, stream>>>(qhi, qlo, khi, klo, mrow, lrowi);
  k_pbm<<<dim3(N_ / TI_, B_), dim3(256), 0, stream>>>(qhi, qlo, khi, klo, vbf, mrow, lrowi, pamT);
  k_ce<<<dim3(64, 8, B_), dim3(256), 0, stream>>>(x, eCp);
  k_cs<<<dim3(B_ * C_), dim3(256), 0, stream>>>(eCp, attnC);
  k_co<<<dim3(16, 8, B_), dim3(256), 0, stream>>>(x, attnC, pamT, gp, gc, out);
}

// Round 18
// 342.313 us; speedup vs baseline: 9.0211x; 1.0400x over previous
//
#include <hip/hip_runtime.h>
#include <hip/hip_bf16.h>

// DA block (DANet) — Round 18: k_co v2 (x-load-latency bound: 1 blk/CU + 1
// outstanding load; fix = j-unroll x8 hoisted loads + 16-ch blocks -> 2 blk/CU).
// Summation order per accumulator unchanged -> bit-identical output.
// All other kernels identical to R17-green. Inputs fp32 dict order; output fp32.

#define B_ 2
#define C_ 256
#define N_ 4096
#define QK_ 32

#define TI_ 32     // i-rows per block (pass A & B)
#define TJ_ 64     // j per tile
#define PP_ 72     // p LDS pitch (bf16) = 144 B

typedef __hip_bfloat16 bf16;
typedef __attribute__((ext_vector_type(8))) short bf16x8f;   // MFMA A/B frag
typedef __attribute__((ext_vector_type(4))) float f32x4;     // MFMA C/D frag

union bf8pack { bf16 h[8]; int4 v; bf16x8f f; };

// ---- k_qk1: partial Q,K projections over a 64-channel chunk ----
__global__ __launch_bounds__(256) void k_qk1(
    const float* __restrict__ x, const float* __restrict__ wq, const float* __restrict__ wk,
    float* __restrict__ qp, float* __restrict__ kp) {
  int b = blockIdx.z;
  int cg = blockIdx.y;                      // 4 chunks of 64 channels
  int n = blockIdx.x * 256 + threadIdx.x;
  float qa[QK_], ka[QK_];
#pragma unroll
  for (int o = 0; o < QK_; o++) { qa[o] = 0.f; ka[o] = 0.f; }
  const float* xp = x + ((size_t)b * C_ + cg * 64) * N_ + n;
  for (int c = 0; c < 64; c++) {
    float xv = xp[(size_t)c * N_];
    int cc = cg * 64 + c;
#pragma unroll
    for (int o = 0; o < QK_; o++) {
      qa[o] += wq[o * C_ + cc] * xv;   // uniform weight loads -> scalar path
      ka[o] += wk[o * C_ + cc] * xv;
    }
  }
  float4* qo = (float4*)(qp + (((size_t)cg * B_ + b) * N_ + n) * QK_);
  float4* ko = (float4*)(kp + (((size_t)cg * B_ + b) * N_ + n) * QK_);
#pragma unroll
  for (int u = 0; u < 8; u++) {
    qo[u] = make_float4(qa[4 * u], qa[4 * u + 1], qa[4 * u + 2], qa[4 * u + 3]);
    ko[u] = make_float4(ka[4 * u], ka[4 * u + 1], ka[4 * u + 2], ka[4 * u + 3]);
  }
}

// ---- k_qk2 v2: combine partials + bias, emit hi/lo bf16 split arrays ----
__global__ __launch_bounds__(256) void k_qk2(
    const float* __restrict__ qp, const float* __restrict__ kp,
    const float* __restrict__ bq, const float* __restrict__ bk,
    bf16* __restrict__ qhi, bf16* __restrict__ qlo,
    bf16* __restrict__ khi, bf16* __restrict__ klo) {
  int t = blockIdx.x * 256 + threadIdx.x;    // b*N + n
  int b = t >> 12, n = t & (N_ - 1);
  float qa[QK_], ka[QK_];
#pragma unroll
  for (int o = 0; o < QK_; o++) { qa[o] = bq[o]; ka[o] = bk[o]; }
#pragma unroll
  for (int cg = 0; cg < 4; cg++) {
    const float4* qs = (const float4*)(qp + (((size_t)cg * B_ + b) * N_ + n) * QK_);
    const float4* ks = (const float4*)(kp + (((size_t)cg * B_ + b) * N_ + n) * QK_);
#pragma unroll
    for (int u = 0; u < 8; u++) {
      float4 q4 = qs[u], k4 = ks[u];
      qa[4 * u] += q4.x; qa[4 * u + 1] += q4.y; qa[4 * u + 2] += q4.z; qa[4 * u + 3] += q4.w;
      ka[4 * u] += k4.x; ka[4 * u + 1] += k4.y; ka[4 * u + 2] += k4.z; ka[4 * u + 3] += k4.w;
    }
  }
  size_t base = (size_t)t * QK_;
#pragma unroll
  for (int g = 0; g < 4; g++) {
    bf8pack qh, ql, kh, kl;
#pragma unroll
    for (int u = 0; u < 8; u++) {
      float qv = qa[g * 8 + u], kv = ka[g * 8 + u];
      bf16 qhh = __float2bfloat16(qv);
      bf16 khh = __float2bfloat16(kv);
      qh.h[u] = qhh; ql.h[u] = __float2bfloat16(qv - __bfloat162float(qhh));
      kh.h[u] = khh; kl.h[u] = __float2bfloat16(kv - __bfloat162float(khh));
    }
    *(int4*)(qhi + base + g * 8) = qh.v;
    *(int4*)(qlo + base + g * 8) = ql.v;
    *(int4*)(khi + base + g * 8) = kh.v;
    *(int4*)(klo + base + g * 8) = kl.v;
  }
}

// ---- k_vbf: V proj -> vbf[b,c,j] bf16; 8 channels/block ----
__global__ __launch_bounds__(256) void k_vbf(
    const float* __restrict__ x, const float* __restrict__ wv, const float* __restrict__ bv,
    bf16* __restrict__ vbf) {
  int b = blockIdx.z;
  int co0 = blockIdx.y * 8;
  int n0 = blockIdx.x * 256;
  int tid = threadIdx.x;
  float acc[8];
#pragma unroll
  for (int o = 0; o < 8; o++) acc[o] = bv[co0 + o];
  const float* xp = x + (size_t)b * C_ * N_ + n0 + tid;
  for (int c = 0; c < C_; c++) {
    float xv = xp[(size_t)c * N_];
#pragma unroll
    for (int o = 0; o < 8; o++) acc[o] += wv[(co0 + o) * C_ + c] * xv;
  }
#pragma unroll
  for (int o = 0; o < 8; o++)
    vbf[((size_t)b * C_ + co0 + o) * N_ + n0 + tid] = __float2bfloat16(acc[o]);
}

// ---- k_pam2 v2: MFMA pass A — direct-global hi/lo frags, no LDS in loop ----
__global__ __launch_bounds__(256) void k_pam2(
    const bf16* __restrict__ qhi, const bf16* __restrict__ qlo,
    const bf16* __restrict__ khi, const bf16* __restrict__ klo,
    float* __restrict__ mrow, float* __restrict__ lrowi) {
  int b = blockIdx.y;
  int i0 = blockIdx.x * TI_;
  int tid = threadIdx.x;
  int lane = tid & 63, wave = tid >> 6;
  int n16 = lane & 15, quad = lane >> 4;

  __shared__ float red_m[4 * 32], red_l[4 * 32];

  bf16x8f ahf[2], alf[2];
#pragma unroll
  for (int ih = 0; ih < 2; ih++) {
    size_t qoff = ((size_t)b * N_ + i0 + ih * 16 + n16) * QK_ + quad * 8;
    ahf[ih] = *(const bf16x8f*)(const void*)(qhi + qoff);
    alf[ih] = *(const bf16x8f*)(const void*)(qlo + qoff);
  }

  float m8[8], l8[8];
#pragma unroll
  for (int k = 0; k < 8; k++) { m8[k] = -3.0e38f; l8[k] = 0.f; }

  const bf16* khb = khi + ((size_t)b * N_ + wave * 16 + n16) * QK_ + quad * 8;
  const bf16* klb = klo + ((size_t)b * N_ + wave * 16 + n16) * QK_ + quad * 8;
  bf16x8f khf = *(const bf16x8f*)(const void*)khb;
  bf16x8f klf = *(const bf16x8f*)(const void*)klb;

  for (int jt = 0; jt < N_ / TJ_; jt++) {
    bf16x8f khn, kln;
    if (jt + 1 < N_ / TJ_) {
      size_t off = (size_t)(jt + 1) * TJ_ * QK_;
      khn = *(const bf16x8f*)(const void*)(khb + off);
      kln = *(const bf16x8f*)(const void*)(klb + off);
    }
#pragma unroll
    for (int ih = 0; ih < 2; ih++) {
      f32x4 z = (f32x4)(0.f);
      z = __builtin_amdgcn_mfma_f32_16x16x32_bf16(ahf[ih], khf, z, 0, 0, 0);
      z = __builtin_amdgcn_mfma_f32_16x16x32_bf16(alf[ih], khf, z, 0, 0, 0);
      z = __builtin_amdgcn_mfma_f32_16x16x32_bf16(ahf[ih], klf, z, 0, 0, 0);
#pragma unroll
      for (int r = 0; r < 4; r++) {
        int k = ih * 4 + r;
        float sv = z[r];
        float nm = fmaxf(m8[k], sv);
        l8[k] = l8[k] * __expf(m8[k] - nm) + __expf(sv - nm);
        m8[k] = nm;
      }
    }
    khf = khn; klf = kln;
  }
#pragma unroll
  for (int d = 1; d < 16; d <<= 1) {
#pragma unroll
    for (int k = 0; k < 8; k++) {
      float om = __shfl_xor(m8[k], d, 64);
      float ol = __shfl_xor(l8[k], d, 64);
      float nm = fmaxf(m8[k], om);
      l8[k] = l8[k] * __expf(m8[k] - nm) + ol * __expf(om - nm);
      m8[k] = nm;
    }
  }
  if (n16 == 0) {
#pragma unroll
    for (int ih = 0; ih < 2; ih++)
#pragma unroll
      for (int r = 0; r < 4; r++) {
        int i = ih * 16 + quad * 4 + r;
        red_m[wave * 32 + i] = m8[ih * 4 + r];
        red_l[wave * 32 + i] = l8[ih * 4 + r];
      }
  }
  __syncthreads();
  if (tid < 32) {
    float wm[4];
    float M = -3.0e38f;
#pragma unroll
    for (int w = 0; w < 4; w++) { wm[w] = red_m[w * 32 + tid]; M = fmaxf(M, wm[w]); }
    float L = 0.f;
#pragma unroll
    for (int w = 0; w < 4; w++) L += red_l[w * 32 + tid] * __expf(wm[w] - M);
    mrow[b * N_ + i0 + tid] = M;
    lrowi[b * N_ + i0 + tid] = 1.0f / L;
  }
}

// ---- k_pbm v4: pamT[b,i,c] = sum_j P(i,j) V[j,c]; LDS = p_s only ----
__global__ __launch_bounds__(256) void k_pbm(
    const bf16* __restrict__ qhi, const bf16* __restrict__ qlo,
    const bf16* __restrict__ khi, const bf16* __restrict__ klo,
    const bf16* __restrict__ vbf,
    const float* __restrict__ mrow, const float* __restrict__ lrowi,
    float* __restrict__ pamT) {
  int b = blockIdx.y;
  int i0 = blockIdx.x * TI_;
  int tid = threadIdx.x;
  int lane = tid & 63, wave = tid >> 6;
  int n16 = lane & 15, quad = lane >> 4;

  __shared__ __align__(16) bf16 p_s[2][32 * PP_];   // double-buffered (cross-wave)

  float mreg[8], lireg[8];
#pragma unroll
  for (int ih = 0; ih < 2; ih++)
#pragma unroll
    for (int r = 0; r < 4; r++) {
      int i = ih * 16 + quad * 4 + r;
      mreg[ih * 4 + r] = mrow[b * N_ + i0 + i];
      lireg[ih * 4 + r] = lrowi[b * N_ + i0 + i];
    }

  bf16x8f ahf[2], alf[2];
#pragma unroll
  for (int ih = 0; ih < 2; ih++) {
    size_t qoff = ((size_t)b * N_ + i0 + ih * 16 + n16) * QK_ + quad * 8;
    ahf[ih] = *(const bf16x8f*)(const void*)(qhi + qoff);
    alf[ih] = *(const bf16x8f*)(const void*)(qlo + qoff);
  }

  f32x4 acc[2][4];
#pragma unroll
  for (int ih = 0; ih < 2; ih++)
#pragma unroll
    for (int cb = 0; cb < 4; cb++) acc[ih][cb] = (f32x4)(0.f);

  const bf16* khb = khi + ((size_t)b * N_ + wave * 16 + n16) * QK_ + quad * 8;
  const bf16* klb = klo + ((size_t)b * N_ + wave * 16 + n16) * QK_ + quad * 8;
  const bf16* vb0 = vbf + ((size_t)b * C_ + wave * 64 + n16) * N_ + quad * 8;

  bf16x8f khf = *(const bf16x8f*)(const void*)khb;
  bf16x8f klf = *(const bf16x8f*)(const void*)klb;
  bf16x8f vcur[4][2];
#pragma unroll
  for (int cb = 0; cb < 4; cb++)
#pragma unroll
    for (int h = 0; h < 2; h++)
      vcur[cb][h] = *(const bf16x8f*)(const void*)(vb0 + (size_t)cb * 16 * N_ + h * 32);

  for (int jt = 0; jt < N_ / TJ_; jt++) {
    bf16x8f khn, kln, vnxt[4][2];
    if (jt + 1 < N_ / TJ_) {
      size_t koff = (size_t)(jt + 1) * TJ_ * QK_;
      khn = *(const bf16x8f*)(const void*)(khb + koff);
      kln = *(const bf16x8f*)(const void*)(klb + koff);
      int jb = (jt + 1) * TJ_;
#pragma unroll
      for (int cb = 0; cb < 4; cb++)
#pragma unroll
        for (int h = 0; h < 2; h++)
          vnxt[cb][h] = *(const bf16x8f*)(const void*)(vb0 + (size_t)cb * 16 * N_ + jb + h * 32);
    }
    f32x4 s[2];
#pragma unroll
    for (int ih = 0; ih < 2; ih++) {
      f32x4 z = (f32x4)(0.f);
      z = __builtin_amdgcn_mfma_f32_16x16x32_bf16(ahf[ih], khf, z, 0, 0, 0);
      z = __builtin_amdgcn_mfma_f32_16x16x32_bf16(alf[ih], khf, z, 0, 0, 0);
      z = __builtin_amdgcn_mfma_f32_16x16x32_bf16(ahf[ih], klf, z, 0, 0, 0);
      s[ih] = z;
    }
    bf16* pbuf = p_s[jt & 1];
#pragma unroll
    for (int ih = 0; ih < 2; ih++)
#pragma unroll
      for (int r = 0; r < 4; r++) {
        int i = ih * 16 + quad * 4 + r;
        float p = __expf(s[ih][r] - mreg[ih * 4 + r]) * lireg[ih * 4 + r];
        pbuf[i * PP_ + wave * 16 + n16] = __float2bfloat16(p);
      }
    __syncthreads();   // the ONE barrier per iter (double-buffered p_s)
    bf16x8f pa0[2], pa1[2];
#pragma unroll
    for (int ih = 0; ih < 2; ih++) {
      pa0[ih] = *(const bf16x8f*)(const void*)(pbuf + (ih * 16 + n16) * PP_ + quad * 8);
      pa1[ih] = *(const bf16x8f*)(const void*)(pbuf + (ih * 16 + n16) * PP_ + 32 + quad * 8);
    }
#pragma unroll
    for (int ih = 0; ih < 2; ih++)
#pragma unroll
      for (int cb = 0; cb < 4; cb++) {
        acc[ih][cb] = __builtin_amdgcn_mfma_f32_16x16x32_bf16(pa0[ih], vcur[cb][0], acc[ih][cb], 0, 0, 0);
        acc[ih][cb] = __builtin_amdgcn_mfma_f32_16x16x32_bf16(pa1[ih], vcur[cb][1], acc[ih][cb], 0, 0, 0);
      }
    khf = khn; klf = kln;
#pragma unroll
    for (int cb = 0; cb < 4; cb++)
#pragma unroll
      for (int h = 0; h < 2; h++) vcur[cb][h] = vnxt[cb][h];
  }
#pragma unroll
  for (int ih = 0; ih < 2; ih++)
#pragma unroll
    for (int cb = 0; cb < 4; cb++) {
      int c = wave * 64 + cb * 16 + n16;
#pragma unroll
      for (int r = 0; r < 4; r++) {
        int i = ih * 16 + quad * 4 + r;
        pamT[((size_t)b * N_ + i0 + i) * C_ + c] = acc[ih][cb][r];
      }
    }
}

// ---- k_ce: CAM energy partials over K-chunks ----
__global__ __launch_bounds__(256) void k_ce(const float* __restrict__ x, float* __restrict__ eCp) {
  int b = blockIdx.z;
  int kc = blockIdx.y;
  int it = blockIdx.x & 7, jt = blockIdx.x >> 3;
  int i0 = it * 32, j0 = jt * 32;
  __shared__ float xi[32 * 65], xj[32 * 65];
  int tid = threadIdx.x;
  int ti2 = (tid & 15) * 2, tj2 = (tid >> 4) * 2;
  float a00 = 0.f, a01 = 0.f, a10 = 0.f, a11 = 0.f;
  for (int n0 = 0; n0 < 512; n0 += 64) {
    __syncthreads();
#pragma unroll
    for (int k = 0; k < 8; k++) {
      int e = k * 256 + tid;
      int r = e >> 6, c = e & 63;
      xi[r * 65 + c] = x[((size_t)b * C_ + i0 + r) * N_ + kc * 512 + n0 + c];
      xj[r * 65 + c] = x[((size_t)b * C_ + j0 + r) * N_ + kc * 512 + n0 + c];
    }
    __syncthreads();
#pragma unroll 4
    for (int n = 0; n < 64; n++) {
      float u0 = xi[ti2 * 65 + n], u1 = xi[(ti2 + 1) * 65 + n];
      float w0 = xj[tj2 * 65 + n], w1 = xj[(tj2 + 1) * 65 + n];
      a00 += u0 * w0; a01 += u0 * w1; a10 += u1 * w0; a11 += u1 * w1;
    }
  }
  float* dst = eCp + (((size_t)kc * B_ + b) * C_ + i0) * C_ + j0;
  dst[(ti2 + 0) * C_ + tj2 + 0] = a00;
  dst[(ti2 + 0) * C_ + tj2 + 1] = a01;
  dst[(ti2 + 1) * C_ + tj2 + 0] = a10;
  dst[(ti2 + 1) * C_ + tj2 + 1] = a11;
}

// ---- k_cs: CAM softmax over -e ----
__global__ __launch_bounds__(256) void k_cs(const float* __restrict__ eCp, float* __restrict__ attnC) {
  int row = blockIdx.x;
  int b = row >> 8, i = row & 255;
  int j = threadIdx.x;
  float e = 0.f;
#pragma unroll
  for (int kc = 0; kc < 8; kc++) e += eCp[(((size_t)kc * B_ + b) * C_ + i) * C_ + j];
  float ne = -e;
  __shared__ float buf[256];
  buf[j] = ne;
  __syncthreads();
  for (int st = 128; st >= 1; st >>= 1) {
    if (j < st) buf[j] = fmaxf(buf[j], buf[j + st]);
    __syncthreads();
  }
  float m = buf[0];
  __syncthreads();
  float p = __expf(ne - m);
  buf[j] = p;
  __syncthreads();
  for (int st = 128; st >= 1; st >>= 1) {
    if (j < st) buf[j] += buf[j + st];
    __syncthreads();
  }
  attnC[(size_t)row * C_ + j] = p / buf[0];
}

// ---- k_co v2: CAM out + combine; 16 ch/block, j-unroll x8 hoisted loads ----
__global__ __launch_bounds__(256) void k_co(
    const float* __restrict__ x, const float* __restrict__ attnC, const float* __restrict__ pamT,
    const float* __restrict__ gpam, const float* __restrict__ gcam, float* __restrict__ out) {
  int b = blockIdx.z, c0 = blockIdx.y * 16, n0 = blockIdx.x * 256;
  int tid = threadIdx.x;
  __shared__ float pam_s[256 * 17];
#pragma unroll
  for (int k = 0; k < 16; k++) {
    int e = k * 256 + tid;
    int r = e >> 4, cc = e & 15;
    pam_s[r * 17 + cc] = pamT[((size_t)b * N_ + n0 + r) * C_ + c0 + cc];
  }
  __syncthreads();
  float acc[16];
#pragma unroll
  for (int i = 0; i < 16; i++) acc[i] = 0.f;
  const float* arow = attnC + ((size_t)b * C_ + c0) * C_;
  for (int j0 = 0; j0 < C_; j0 += 8) {
    float xv[8];
#pragma unroll
    for (int u = 0; u < 8; u++)          // 8 independent loads in flight
      xv[u] = x[((size_t)b * C_ + j0 + u) * N_ + n0 + tid];
#pragma unroll
    for (int i = 0; i < 16; i++)
#pragma unroll
      for (int u = 0; u < 8; u++)        // ascending j per acc[i] -> same order
        acc[i] += arow[i * C_ + j0 + u] * xv[u];
  }
  float gp = gpam[0], gc = gcam[0];
#pragma unroll
  for (int i = 0; i < 16; i++) {
    size_t idx = ((size_t)b * C_ + c0 + i) * N_ + n0 + tid;
    out[idx] = gp * pam_s[tid * 17 + i] + gc * acc[i] + 2.0f * x[idx];
  }
}

extern "C" void kernel_launch(void* const* d_in, const int* in_sizes, int n_in,
                              void* d_out, int out_size, void* d_ws, size_t ws_size,
                              hipStream_t stream) {
  const float* x  = (const float*)d_in[0];
  const float* wq = (const float*)d_in[1];
  const float* bq = (const float*)d_in[2];
  const float* wk = (const float*)d_in[3];
  const float* bk = (const float*)d_in[4];
  const float* wv = (const float*)d_in[5];
  const float* bv = (const float*)d_in[6];
  const float* gp = (const float*)d_in[7];
  const float* gc = (const float*)d_in[8];
  float* out = (float*)d_out;

  float* ws = (float*)d_ws;
  size_t o = 0;
  float* pamT  = ws + o; o += (size_t)B_ * N_ * C_;     // 2097152
  float* mrow  = ws + o; o += (size_t)B_ * N_;          // 8192
  float* lrowi = ws + o; o += (size_t)B_ * N_;          // 8192
  float* eCp   = ws + o; o += (size_t)8 * B_ * C_ * C_; // 1048576
  float* attnC = ws + o; o += (size_t)B_ * C_ * C_;     // 131072
  bf16*  vbf   = (bf16*)(ws + o); o += (size_t)B_ * N_ * C_ / 2;   // 1048576
  bf16*  qhi   = (bf16*)(ws + o); o += (size_t)B_ * N_ * QK_ / 2;  // 131072
  bf16*  qlo   = (bf16*)(ws + o); o += (size_t)B_ * N_ * QK_ / 2;  // 131072
  bf16*  khi   = (bf16*)(ws + o); o += (size_t)B_ * N_ * QK_ / 2;  // 131072
  bf16*  klo   = (bf16*)(ws + o); o += (size_t)B_ * N_ * QK_ / 2;  // 131072
  float* qpprt = ws + o; o += (size_t)4 * B_ * N_ * QK_; // 1048576
  float* kpprt = ws + o; o += (size_t)4 * B_ * N_ * QK_; // 1048576
  // total ~6.8 M floats = 27.3 MB

  k_qk1<<<dim3(16, 4, B_), dim3(256), 0, stream>>>(x, wq, wk, qpprt, kpprt);
  k_qk2<<<dim3(32), dim3(256), 0, stream>>>(qpprt, kpprt, bq, bk, qhi, qlo, khi, klo);
  k_vbf<<<dim3(16, 32, B_), dim3(256), 0, stream>>>(x, wv, bv, vbf);
  k_pam2<<<dim3(N_ / TI_, B_), dim3(256), 0, stream>>>(qhi, qlo, khi, klo, mrow, lrowi);
  k_pbm<<<dim3(N_ / TI_, B_), dim3(256), 0, stream>>>(qhi, qlo, khi, klo, vbf, mrow, lrowi, pamT);
  k_ce<<<dim3(64, 8, B_), dim3(256), 0, stream>>>(x, eCp);
  k_cs<<<dim3(B_ * C_), dim3(256), 0, stream>>>(eCp, attnC);
  k_co<<<dim3(16, 16, B_), dim3(256), 0, stream>>>(x, attnC, pamT, gp, gc, out);
}